// Round 1
// baseline (3939.039 us; speedup 1.0000x reference)
//
#include <hip/hip_runtime.h>
#include <math.h>

#define NN 8192
#define HIDD 768
#define NCLS 18
#define OD 512          // HEADS*GD = 2*256
#define ETOT 342        // 324 class edges + 18 self loops
#define NSPLIT 4
#define NEG 0.2f
#define LN_EPS 1e-5f

// ---------- sorted top-5 insert (all static indices, stays in registers) ----
__device__ __forceinline__ void top5_insert(float s, int idx,
    float& d0, float& d1, float& d2, float& d3, float& d4,
    int& i0, int& i1, int& i2, int& i3, int& i4) {
  if (s >= d4) return;
  if (s < d3) {
    d4 = d3; i4 = i3;
    if (s < d2) {
      d3 = d2; i3 = i2;
      if (s < d1) {
        d2 = d1; i2 = i1;
        if (s < d0) { d1 = d0; i1 = i0; d0 = s; i0 = idx; }
        else        { d1 = s;  i1 = idx; }
      } else { d2 = s; i2 = idx; }
    } else { d3 = s; i3 = idx; }
  } else { d4 = s; i4 = idx; }
}

// ---------- row squared norms ------------------------------------------------
__global__ __launch_bounds__(256) void rownorm_kernel(const float* __restrict__ X,
                                                      float* __restrict__ x2) {
  int row = blockIdx.x * 4 + (threadIdx.x >> 6);
  int lane = threadIdx.x & 63;
  const float* xr = X + (size_t)row * HIDD;
  float s = 0.f;
  for (int k = lane; k < HIDD; k += 64) { float v = xr[k]; s += v * v; }
  #pragma unroll
  for (int off = 32; off; off >>= 1) s += __shfl_down(s, off);
  if (lane == 0) x2[row] = s;
}

// ---------- small Y = X @ W^T + b (thread per output) ------------------------
__global__ void small_lin_kernel(const float* __restrict__ X, const float* __restrict__ W,
                                 const float* __restrict__ b, float* __restrict__ Y,
                                 int n, int K, int O) {
  int idx = blockIdx.x * 256 + threadIdx.x;
  if (idx >= n * O) return;
  int row = idx / O, o = idx - row * O;
  const float* xr = X + (size_t)row * K;
  const float* wr = W + (size_t)o * K;
  float acc = 0.f;
  for (int k = 0; k < K; ++k) acc += xr[k] * wr[k];
  Y[idx] = acc + b[o];
}

// ---------- small C = A @ B (thread per output) ------------------------------
__global__ void small_nn_kernel(const float* __restrict__ A, const float* __restrict__ B,
                                float* __restrict__ C, int M, int K, int Nc) {
  int idx = blockIdx.x * 256 + threadIdx.x;
  if (idx >= M * Nc) return;
  int i = idx / Nc, j = idx - i * Nc;
  float acc = 0.f;
  for (int k = 0; k < K; ++k) acc += A[(size_t)i * K + k] * B[(size_t)k * Nc + j];
  C[idx] = acc;
}

// ---------- class-graph GATv2 -> mean over nodes (single block) --------------
__global__ __launch_bounds__(256) void class_gat_kernel(const int* __restrict__ ei,
    const float* __restrict__ xlc, const float* __restrict__ xrc,
    const float* __restrict__ att, const float* __restrict__ bias,
    float* __restrict__ cmean) {
  __shared__ float sc[ETOT * 2];
  __shared__ int es[ETOT], ed[ETOT];
  __shared__ float mx[NCLS][2], sm[NCLS][2];
  int tid = threadIdx.x;
  for (int e = tid; e < ETOT; e += 256) {
    if (e < 324) { es[e] = ei[e]; ed[e] = ei[324 + e]; }
    else         { es[e] = e - 324; ed[e] = e - 324; }
  }
  __syncthreads();
  int lane = tid & 63, w = tid >> 6;
  for (int t = w; t < ETOT * 2; t += 4) {
    int e = t >> 1, h = t & 1;
    const float* xlr = xlc + (size_t)es[e] * OD + h * 256;
    const float* xrr = xrc + (size_t)ed[e] * OD + h * 256;
    const float* ar  = att + h * 256;
    float s = 0.f;
    for (int d = lane; d < 256; d += 64) {
      float v = xlr[d] + xrr[d];
      v = v > 0.f ? v : NEG * v;
      s += v * ar[d];
    }
    #pragma unroll
    for (int off = 32; off; off >>= 1) s += __shfl_down(s, off);
    if (lane == 0) sc[t] = s;
  }
  __syncthreads();
  if (tid < NCLS * 2) {
    int d = tid >> 1, h = tid & 1;
    float m = -3e38f;
    for (int e = 0; e < ETOT; ++e) if (ed[e] == d) m = fmaxf(m, sc[e * 2 + h]);
    float ssum = 0.f;
    for (int e = 0; e < ETOT; ++e) if (ed[e] == d) ssum += expf(sc[e * 2 + h] - m);
    mx[d][h] = m; sm[d][h] = 1.f / ssum;
  }
  __syncthreads();
  for (int t = tid; t < ETOT * 2; t += 256) {
    int e = t >> 1, h = t & 1;
    sc[t] = expf(sc[t] - mx[ed[e]][h]) * sm[ed[e]][h];
  }
  __syncthreads();
  for (int c = tid; c < OD; c += 256) {
    int h = c >> 8;
    float acc = 0.f;
    for (int e = 0; e < ETOT; ++e) acc += sc[e * 2 + h] * xlc[(size_t)es[e] * OD + c];
    cmean[c] = acc * (1.f / 18.f) + bias[c];
  }
}

// ---------- fused distance GEMM + per-row top-5 (partial over column split) --
__global__ __launch_bounds__(256) void dist_topk_kernel(const float* __restrict__ X,
    const float* __restrict__ x2, float* __restrict__ pdist, int* __restrict__ pidx) {
  __shared__ float As[32][65];
  __shared__ float Bs[32][65];
  __shared__ float Ds[64][65];
  __shared__ float c2s[64];
  const int r0 = blockIdx.x * 64;
  const int cols = NN / NSPLIT;
  const int jbase = blockIdx.y * cols;
  const int tid = threadIdx.x;
  const int tx = tid & 15, ty = tid >> 4;
  float d0 = 3e38f, d1 = 3e38f, d2 = 3e38f, d3 = 3e38f, d4 = 3e38f;
  int i0 = 0, i1 = 0, i2 = 0, i3 = 0, i4 = 0;
  for (int jt = 0; jt < cols; jt += 64) {
    const int j0 = jbase + jt;
    if (tid < 64) c2s[tid] = x2[j0 + tid];
    float acc[4][4] = {};
    for (int kt = 0; kt < HIDD; kt += 32) {
      #pragma unroll
      for (int l = 0; l < 8; ++l) {
        int idx = l * 256 + tid;
        int m = idx >> 5, k = idx & 31;
        As[k][m] = X[(size_t)(r0 + m) * HIDD + kt + k];
        Bs[k][m] = X[(size_t)(j0 + m) * HIDD + kt + k];
      }
      __syncthreads();
      #pragma unroll
      for (int k = 0; k < 32; ++k) {
        float a[4], b[4];
        #pragma unroll
        for (int i = 0; i < 4; ++i) a[i] = As[k][ty * 4 + i];
        #pragma unroll
        for (int j = 0; j < 4; ++j) b[j] = Bs[k][tx * 4 + j];
        #pragma unroll
        for (int i = 0; i < 4; ++i)
          #pragma unroll
          for (int j = 0; j < 4; ++j) acc[i][j] += a[i] * b[j];
      }
      __syncthreads();
    }
    // score = x2[j] - 2*dot  (x2[i] is a per-row constant: same ranking)
    #pragma unroll
    for (int i = 0; i < 4; ++i)
      #pragma unroll
      for (int j = 0; j < 4; ++j)
        Ds[ty * 4 + i][tx * 4 + j] = c2s[tx * 4 + j] - 2.f * acc[i][j];
    __syncthreads();
    if (tid < 64) {
      for (int n = 0; n < 64; ++n) {
        float s = Ds[tid][n];
        top5_insert(s, j0 + n, d0, d1, d2, d3, d4, i0, i1, i2, i3, i4);
      }
    }
    __syncthreads();
  }
  if (tid < 64) {
    size_t base = ((size_t)(r0 + tid) * NSPLIT + blockIdx.y) * 5;
    pdist[base + 0] = d0; pdist[base + 1] = d1; pdist[base + 2] = d2;
    pdist[base + 3] = d3; pdist[base + 4] = d4;
    pidx[base + 0] = i0; pidx[base + 1] = i1; pidx[base + 2] = i2;
    pidx[base + 3] = i3; pidx[base + 4] = i4;
  }
}

// ---------- merge NSPLIT partial top-5 lists per row -------------------------
__global__ void knn_merge_kernel(const float* __restrict__ pdist,
                                 const int* __restrict__ pidx, int* __restrict__ knn) {
  int i = blockIdx.x * 256 + threadIdx.x;
  if (i >= NN) return;
  float d0 = 3e38f, d1 = 3e38f, d2 = 3e38f, d3 = 3e38f, d4 = 3e38f;
  int i0 = 0, i1 = 0, i2 = 0, i3 = 0, i4 = 0;
  for (int s = 0; s < NSPLIT * 5; ++s) {
    float d = pdist[(size_t)i * NSPLIT * 5 + s];
    int ix = pidx[(size_t)i * NSPLIT * 5 + s];
    top5_insert(d, ix, d0, d1, d2, d3, d4, i0, i1, i2, i3, i4);
  }
  knn[i * 5 + 0] = i0; knn[i * 5 + 1] = i1; knn[i * 5 + 2] = i2;
  knn[i * 5 + 3] = i3; knn[i * 5 + 4] = i4;
}

// ---------- tiled fp32 GEMM: C[M,N] = A[M,K] @ B[N,K]^T + bias[N] ------------
__global__ __launch_bounds__(256) void gemm_nt_bias_kernel(const float* __restrict__ A,
    const float* __restrict__ B, const float* __restrict__ bias, float* __restrict__ C,
    int M, int Nc, int K) {
  __shared__ float As[32][65];
  __shared__ float Bs[32][65];
  int r0 = blockIdx.x * 64, c0 = blockIdx.y * 64;
  int tid = threadIdx.x, tx = tid & 15, ty = tid >> 4;
  float acc[4][4] = {};
  for (int kt = 0; kt < K; kt += 32) {
    #pragma unroll
    for (int l = 0; l < 8; ++l) {
      int idx = l * 256 + tid;
      int m = idx >> 5, k = idx & 31;
      As[k][m] = A[(size_t)(r0 + m) * K + kt + k];
      Bs[k][m] = B[(size_t)(c0 + m) * K + kt + k];
    }
    __syncthreads();
    #pragma unroll
    for (int k = 0; k < 32; ++k) {
      float a[4], b[4];
      #pragma unroll
      for (int i = 0; i < 4; ++i) a[i] = As[k][ty * 4 + i];
      #pragma unroll
      for (int j = 0; j < 4; ++j) b[j] = Bs[k][tx * 4 + j];
      #pragma unroll
      for (int i = 0; i < 4; ++i)
        #pragma unroll
        for (int j = 0; j < 4; ++j) acc[i][j] += a[i] * b[j];
    }
    __syncthreads();
  }
  #pragma unroll
  for (int i = 0; i < 4; ++i) {
    int r = r0 + ty * 4 + i;
    #pragma unroll
    for (int j = 0; j < 4; ++j) {
      int c = c0 + tx * 4 + j;
      C[(size_t)r * Nc + c] = acc[i][j] + bias[c];
    }
  }
}

// ---------- instance GATv2 aggregation over 6 edges + ctx = agg + cmean ------
__global__ __launch_bounds__(256) void inst_gat_kernel(const float* __restrict__ xl,
    const float* __restrict__ xr, const int* __restrict__ knn,
    const float* __restrict__ att, const float* __restrict__ bias,
    const float* __restrict__ cmean, float* __restrict__ ctx) {
  __shared__ float sc[12];
  __shared__ float alpha[12];
  __shared__ int nbr[6];
  const int i = blockIdx.x;
  const int tid = threadIdx.x;
  if (tid < 5) nbr[tid] = knn[i * 5 + tid];
  else if (tid == 5) nbr[5] = i;   // explicit self loop (in addition to knn self)
  __syncthreads();
  int lane = tid & 63, w = tid >> 6;
  for (int t = w; t < 12; t += 4) {
    int e = t >> 1, h = t & 1;
    const float* xlr = xl + (size_t)nbr[e] * OD + h * 256;
    const float* xrr = xr + (size_t)i * OD + h * 256;
    const float* ar  = att + h * 256;
    float s = 0.f;
    #pragma unroll
    for (int q = 0; q < 4; ++q) {
      int d = lane + q * 64;
      float v = xlr[d] + xrr[d];
      v = v > 0.f ? v : NEG * v;
      s += v * ar[d];
    }
    #pragma unroll
    for (int off = 32; off; off >>= 1) s += __shfl_down(s, off);
    if (lane == 0) sc[t] = s;
  }
  __syncthreads();
  if (tid < 2) {
    int h = tid;
    float m = -3e38f;
    #pragma unroll
    for (int e = 0; e < 6; ++e) m = fmaxf(m, sc[e * 2 + h]);
    float ssum = 0.f;
    #pragma unroll
    for (int e = 0; e < 6; ++e) { float ex = expf(sc[e * 2 + h] - m); alpha[e * 2 + h] = ex; ssum += ex; }
    float inv = 1.f / ssum;
    #pragma unroll
    for (int e = 0; e < 6; ++e) alpha[e * 2 + h] *= inv;
  }
  __syncthreads();
  for (int c = tid; c < OD; c += 256) {
    int h = c >> 8;
    float acc = 0.f;
    #pragma unroll
    for (int e = 0; e < 6; ++e) acc += alpha[e * 2 + h] * xl[(size_t)nbr[e] * OD + c];
    ctx[(size_t)i * OD + c] = acc + bias[c] + cmean[c];
  }
}

// ---------- fused epilogue: LN1 -> LN2 -> GELU -> 18-way classifier ----------
__global__ __launch_bounds__(256) void epilogue_kernel(const float* __restrict__ inst,
    const float* __restrict__ attn, const float* __restrict__ g1, const float* __restrict__ b1,
    const float* __restrict__ g2, const float* __restrict__ b2, const float* __restrict__ gw,
    const float* __restrict__ gb, const float* __restrict__ temp, float* __restrict__ out) {
  __shared__ float buf[HIDD];
  __shared__ float red[4];
  const int i = blockIdx.x;
  const int tid = threadIdx.x;
  const int lane = tid & 63, w = tid >> 6;
  size_t base = (size_t)i * HIDD;
  float v0 = inst[base + tid]       + attn[base + tid];
  float v1 = inst[base + tid + 256] + attn[base + tid + 256];
  float v2 = inst[base + tid + 512] + attn[base + tid + 512];

  // LN1 mean
  float s = v0 + v1 + v2;
  #pragma unroll
  for (int off = 32; off; off >>= 1) s += __shfl_down(s, off);
  if (lane == 0) red[w] = s;
  __syncthreads();
  float mean = (red[0] + red[1] + red[2] + red[3]) * (1.f / HIDD);
  __syncthreads();
  float e0 = v0 - mean, e1 = v1 - mean, e2 = v2 - mean;
  s = e0 * e0 + e1 * e1 + e2 * e2;
  #pragma unroll
  for (int off = 32; off; off >>= 1) s += __shfl_down(s, off);
  if (lane == 0) red[w] = s;
  __syncthreads();
  float rstd = rsqrtf((red[0] + red[1] + red[2] + red[3]) * (1.f / HIDD) + LN_EPS);
  __syncthreads();
  float y0 = e0 * rstd * g1[tid]       + b1[tid];
  float y1 = e1 * rstd * g1[tid + 256] + b1[tid + 256];
  float y2 = e2 * rstd * g1[tid + 512] + b1[tid + 512];

  // LN2
  s = y0 + y1 + y2;
  #pragma unroll
  for (int off = 32; off; off >>= 1) s += __shfl_down(s, off);
  if (lane == 0) red[w] = s;
  __syncthreads();
  float mean2 = (red[0] + red[1] + red[2] + red[3]) * (1.f / HIDD);
  __syncthreads();
  float f0 = y0 - mean2, f1 = y1 - mean2, f2 = y2 - mean2;
  s = f0 * f0 + f1 * f1 + f2 * f2;
  #pragma unroll
  for (int off = 32; off; off >>= 1) s += __shfl_down(s, off);
  if (lane == 0) red[w] = s;
  __syncthreads();
  float rstd2 = rsqrtf((red[0] + red[1] + red[2] + red[3]) * (1.f / HIDD) + LN_EPS);
  float z0 = f0 * rstd2 * g2[tid]       + b2[tid];
  float z1 = f1 * rstd2 * g2[tid + 256] + b2[tid + 256];
  float z2 = f2 * rstd2 * g2[tid + 512] + b2[tid + 512];
  // exact GELU
  buf[tid]       = 0.5f * z0 * (1.f + erff(z0 * 0.70710678118654752f));
  buf[tid + 256] = 0.5f * z1 * (1.f + erff(z1 * 0.70710678118654752f));
  buf[tid + 512] = 0.5f * z2 * (1.f + erff(z2 * 0.70710678118654752f));
  __syncthreads();

  float invT = 1.f / temp[0];
  for (int c = w; c < NCLS; c += 4) {
    const float* wr = gw + (size_t)c * HIDD;
    float acc = 0.f;
    for (int d = lane; d < HIDD; d += 64) acc += buf[d] * wr[d];
    #pragma unroll
    for (int off = 32; off; off >>= 1) acc += __shfl_down(acc, off);
    if (lane == 0) out[(size_t)i * NCLS + c] = (acc + gb[c]) * invT;
  }
}

// ---------------------------------------------------------------------------
extern "C" void kernel_launch(void* const* d_in, const int* in_sizes, int n_in,
                              void* d_out, int out_size, void* d_ws, size_t ws_size,
                              hipStream_t stream) {
  (void)in_sizes; (void)n_in; (void)out_size; (void)ws_size;
  const float* X       = (const float*)d_in[0];
  const int*   cei     = (const int*)  d_in[1];
  const float* cemb    = (const float*)d_in[2];
  const float* gc_wl   = (const float*)d_in[3];
  const float* gc_bl   = (const float*)d_in[4];
  const float* gc_wr   = (const float*)d_in[5];
  const float* gc_br   = (const float*)d_in[6];
  const float* gc_att  = (const float*)d_in[7];
  const float* gc_bias = (const float*)d_in[8];
  const float* gi_wl   = (const float*)d_in[9];
  const float* gi_bl   = (const float*)d_in[10];
  const float* gi_wr   = (const float*)d_in[11];
  const float* gi_br   = (const float*)d_in[12];
  const float* gi_att  = (const float*)d_in[13];
  const float* gi_bias = (const float*)d_in[14];
  // d_in[15]=q_w, d_in[16]=q_b: cancel out of the forward value (seq_len 1)
  const float* ctx_w   = (const float*)d_in[17];
  const float* ctx_b   = (const float*)d_in[18];
  const float* wv      = (const float*)d_in[19];
  const float* bv      = (const float*)d_in[20];
  const float* wo      = (const float*)d_in[21];
  const float* bo      = (const float*)d_in[22];
  const float* ln1_g   = (const float*)d_in[23];
  const float* ln1_b   = (const float*)d_in[24];
  const float* ln2_g   = (const float*)d_in[25];
  const float* ln2_b   = (const float*)d_in[26];
  const float* gw_w    = (const float*)d_in[27];
  const float* gw_b    = (const float*)d_in[28];
  const float* temp    = (const float*)d_in[29];
  float* out = (float*)d_out;

  // workspace layout (floats): total ~55 MB
  float* ws    = (float*)d_ws;
  float* xl    = ws;                               // 8192*512
  float* xr    = xl + (size_t)NN * OD;             // 8192*512
  float* ctx   = xr + (size_t)NN * OD;             // 8192*512
  float* x2    = ctx + (size_t)NN * OD;            // 8192
  float* pdist = x2 + NN;                          // 8192*NSPLIT*5
  int*   pidx  = (int*)(pdist + (size_t)NN * NSPLIT * 5);
  int*   knn   = pidx + (size_t)NN * NSPLIT * 5;   // 8192*5
  float* xlc   = (float*)(knn + NN * 5);           // 18*512
  float* xrc   = xlc + NCLS * OD;                  // 18*512
  float* cmean = xrc + NCLS * OD;                  // 512
  float* T1    = cmean + OD;                       // 768*512
  float* W3    = T1 + (size_t)HIDD * OD;           // 768*512
  float* t1b   = W3 + (size_t)HIDD * OD;           // 768
  float* bp    = t1b + HIDD;                       // 768
  float* attnb = xl;  // alias: attn [8192,768] overlays xl+xr (dead by then)

  // --- class path -> cmean[512] ---
  small_lin_kernel<<<(NCLS * OD + 255) / 256, 256, 0, stream>>>(cemb, gc_wl, gc_bl, xlc, NCLS, HIDD, OD);
  small_lin_kernel<<<(NCLS * OD + 255) / 256, 256, 0, stream>>>(cemb, gc_wr, gc_br, xrc, NCLS, HIDD, OD);
  class_gat_kernel<<<1, 256, 0, stream>>>(cei, xlc, xrc, gc_att, gc_bias, cmean);

  // --- kNN graph ---
  rownorm_kernel<<<NN / 4, 256, 0, stream>>>(X, x2);
  dist_topk_kernel<<<dim3(NN / 64, NSPLIT), 256, 0, stream>>>(X, x2, pdist, pidx);
  knn_merge_kernel<<<NN / 256, 256, 0, stream>>>(pdist, pidx, knn);

  // --- instance GATv2 ---
  gemm_nt_bias_kernel<<<dim3(NN / 64, OD / 64), 256, 0, stream>>>(X, gi_wl, gi_bl, xl, NN, OD, HIDD);
  gemm_nt_bias_kernel<<<dim3(NN / 64, OD / 64), 256, 0, stream>>>(X, gi_wr, gi_br, xr, NN, OD, HIDD);
  inst_gat_kernel<<<NN, 256, 0, stream>>>(xl, xr, knn, gi_att, gi_bias, cmean, ctx);

  // --- fold attention chain: attn = ctx @ (wo@wv@ctx_w)^T + b' ---
  small_nn_kernel<<<(HIDD * OD + 255) / 256, 256, 0, stream>>>(wv, ctx_w, T1, HIDD, HIDD, OD);
  small_nn_kernel<<<(HIDD * OD + 255) / 256, 256, 0, stream>>>(wo, T1, W3, HIDD, HIDD, OD);
  small_lin_kernel<<<(HIDD + 255) / 256, 256, 0, stream>>>(ctx_b, wv, bv, t1b, 1, HIDD, HIDD);
  small_lin_kernel<<<(HIDD + 255) / 256, 256, 0, stream>>>(t1b, wo, bo, bp, 1, HIDD, HIDD);
  gemm_nt_bias_kernel<<<dim3(NN / 64, HIDD / 64), 256, 0, stream>>>(ctx, W3, bp, attnb, NN, HIDD, OD);

  // --- LN -> LN -> GELU -> classifier ---
  epilogue_kernel<<<NN, 256, 0, stream>>>(X, attnb, ln1_g, ln1_b, ln2_g, ln2_b, gw_w, gw_b, temp, out);
}

// Round 2
// 2451.340 us; speedup vs baseline: 1.6069x; 1.6069x over previous
//
#include <hip/hip_runtime.h>
#include <hip/hip_bf16.h>
#include <math.h>

#define NN 8192
#define HIDD 768
#define NCLS 18
#define OD 512          // HEADS*GD = 2*256
#define ETOT 342        // 324 class edges + 18 self loops
#define NSPLIT 8
#define NEG 0.2f
#define LN_EPS 1e-5f

typedef __attribute__((ext_vector_type(8))) short bf16x8;
typedef __attribute__((ext_vector_type(4))) float f32x4;

// ---------- sorted top-5 insert (all static indices, stays in registers) ----
__device__ __forceinline__ void top5_insert(float s, int idx,
    float& d0, float& d1, float& d2, float& d3, float& d4,
    int& i0, int& i1, int& i2, int& i3, int& i4) {
  if (s >= d4) return;
  if (s < d3) {
    d4 = d3; i4 = i3;
    if (s < d2) {
      d3 = d2; i3 = i2;
      if (s < d1) {
        d2 = d1; i2 = i1;
        if (s < d0) { d1 = d0; i1 = i0; d0 = s; i0 = idx; }
        else        { d1 = s;  i1 = idx; }
      } else { d2 = s; i2 = idx; }
    } else { d3 = s; i3 = idx; }
  } else { d4 = s; i4 = idx; }
}

// ---------- async global->LDS 16B ------------------------------------------
__device__ __forceinline__ void stage16(const void* g, void* l) {
  __builtin_amdgcn_global_load_lds(
      (const __attribute__((address_space(1))) unsigned int*)g,
      (__attribute__((address_space(3))) unsigned int*)l, 16, 0, 0);
}

// ---------- split fp32 -> bf16 hi/lo ----------------------------------------
__global__ __launch_bounds__(256) void split_kernel(const float* __restrict__ X,
    ushort* __restrict__ Xh, ushort* __restrict__ Xl) {
  int i = blockIdx.x * 256 + threadIdx.x;
  float4 v = ((const float4*)X)[i];
  float vv[4] = {v.x, v.y, v.z, v.w};
  ushort h[4], l[4];
  #pragma unroll
  for (int j = 0; j < 4; ++j) {
    __hip_bfloat16 hb = __float2bfloat16(vv[j]);
    float hf = __bfloat162float(hb);
    __hip_bfloat16 lb = __float2bfloat16(vv[j] - hf);
    h[j] = *(ushort*)&hb;
    l[j] = *(ushort*)&lb;
  }
  ((ushort4*)Xh)[i] = make_ushort4(h[0], h[1], h[2], h[3]);
  ((ushort4*)Xl)[i] = make_ushort4(l[0], l[1], l[2], l[3]);
}

// ---------- row squared norms ------------------------------------------------
__global__ __launch_bounds__(256) void rownorm_kernel(const float* __restrict__ X,
                                                      float* __restrict__ x2) {
  int row = blockIdx.x * 4 + (threadIdx.x >> 6);
  int lane = threadIdx.x & 63;
  const float* xr = X + (size_t)row * HIDD;
  float s = 0.f;
  for (int k = lane; k < HIDD; k += 64) { float v = xr[k]; s += v * v; }
  #pragma unroll
  for (int off = 32; off; off >>= 1) s += __shfl_down(s, off);
  if (lane == 0) x2[row] = s;
}

// ---------- small Y = X @ W^T + b (thread per output) ------------------------
__global__ void small_lin_kernel(const float* __restrict__ X, const float* __restrict__ W,
                                 const float* __restrict__ b, float* __restrict__ Y,
                                 int n, int K, int O) {
  int idx = blockIdx.x * 256 + threadIdx.x;
  if (idx >= n * O) return;
  int row = idx / O, o = idx - row * O;
  const float* xr = X + (size_t)row * K;
  const float* wr = W + (size_t)o * K;
  float acc = 0.f;
  for (int k = 0; k < K; ++k) acc += xr[k] * wr[k];
  Y[idx] = acc + b[o];
}

// ---------- small C = A @ B (thread per output) ------------------------------
__global__ void small_nn_kernel(const float* __restrict__ A, const float* __restrict__ B,
                                float* __restrict__ C, int M, int K, int Nc) {
  int idx = blockIdx.x * 256 + threadIdx.x;
  if (idx >= M * Nc) return;
  int i = idx / Nc, j = idx - i * Nc;
  float acc = 0.f;
  for (int k = 0; k < K; ++k) acc += A[(size_t)i * K + k] * B[(size_t)k * Nc + j];
  C[idx] = acc;
}

// ---------- class-graph GATv2 -> mean over nodes (single block) --------------
__global__ __launch_bounds__(256) void class_gat_kernel(const int* __restrict__ ei,
    const float* __restrict__ xlc, const float* __restrict__ xrc,
    const float* __restrict__ att, const float* __restrict__ bias,
    float* __restrict__ cmean) {
  __shared__ float sc[ETOT * 2];
  __shared__ int es[ETOT], ed[ETOT];
  __shared__ float mx[NCLS][2], sm[NCLS][2];
  int tid = threadIdx.x;
  for (int e = tid; e < ETOT; e += 256) {
    if (e < 324) { es[e] = ei[e]; ed[e] = ei[324 + e]; }
    else         { es[e] = e - 324; ed[e] = e - 324; }
  }
  __syncthreads();
  int lane = tid & 63, w = tid >> 6;
  for (int t = w; t < ETOT * 2; t += 4) {
    int e = t >> 1, h = t & 1;
    const float* xlr = xlc + (size_t)es[e] * OD + h * 256;
    const float* xrr = xrc + (size_t)ed[e] * OD + h * 256;
    const float* ar  = att + h * 256;
    float s = 0.f;
    for (int d = lane; d < 256; d += 64) {
      float v = xlr[d] + xrr[d];
      v = v > 0.f ? v : NEG * v;
      s += v * ar[d];
    }
    #pragma unroll
    for (int off = 32; off; off >>= 1) s += __shfl_down(s, off);
    if (lane == 0) sc[t] = s;
  }
  __syncthreads();
  if (tid < NCLS * 2) {
    int d = tid >> 1, h = tid & 1;
    float m = -3e38f;
    for (int e = 0; e < ETOT; ++e) if (ed[e] == d) m = fmaxf(m, sc[e * 2 + h]);
    float ssum = 0.f;
    for (int e = 0; e < ETOT; ++e) if (ed[e] == d) ssum += expf(sc[e * 2 + h] - m);
    mx[d][h] = m; sm[d][h] = 1.f / ssum;
  }
  __syncthreads();
  for (int t = tid; t < ETOT * 2; t += 256) {
    int e = t >> 1, h = t & 1;
    sc[t] = expf(sc[t] - mx[ed[e]][h]) * sm[ed[e]][h];
  }
  __syncthreads();
  for (int c = tid; c < OD; c += 256) {
    int h = c >> 8;
    float acc = 0.f;
    for (int e = 0; e < ETOT; ++e) acc += sc[e * 2 + h] * xlc[(size_t)es[e] * OD + c];
    cmean[c] = acc * (1.f / 18.f) + bias[c];
  }
}

// ---------- MFMA split-bf16 distance GEMM + fused per-row top-5 --------------
// 128x128 tile / block (4 waves of 64x64), BK=64, col space split NSPLIT ways.
__global__ __launch_bounds__(256) void dist_topk_mfma(
    const ushort* __restrict__ Xh, const ushort* __restrict__ Xl,
    const float* __restrict__ x2, float* __restrict__ pdist, int* __restrict__ pidx) {
  __shared__ char lds[65536];           // union: 4x16KB staging | 128x128 f32 scores
  char* const pAh = lds;
  char* const pAl = lds + 16384;
  char* const pBh = lds + 32768;
  char* const pBl = lds + 49152;
  float* const Ds = (float*)lds;

  const int tid = threadIdx.x;
  const int lane = tid & 63, wid = tid >> 6;
  const int fr = lane & 15, fq = lane >> 4;
  const int r0 = blockIdx.x * 128;
  const int jgrp = blockIdx.y;
  const int wr = (wid >> 1) * 64, wc = (wid & 1) * 64;

  float d0 = 3e38f, d1 = 3e38f, d2 = 3e38f, d3 = 3e38f, d4 = 3e38f;
  int i0 = 0, i1 = 0, i2 = 0, i3 = 0, i4 = 0;

  for (int jt = 0; jt < NN / NSPLIT; jt += 128) {
    const int c0 = jgrp * (NN / NSPLIT) + jt;
    f32x4 acc[4][4] = {};
    for (int kt = 0; kt < HIDD; kt += 64) {
      __syncthreads();                         // prior LDS consumers done
      // stage Ah/Al/Bh/Bl [128 rows][64 bf16]; source pre-swizzled so that
      // swizzled ds_read (chunk ^= row&7) sees the right data (rule #21)
      #pragma unroll
      for (int q = 0; q < 4; ++q) {
        const int chunk = wid * 256 + q * 64 + lane;
        const int row = chunk >> 3;
        const int lc = (chunk & 7) ^ (row & 7);
        const size_t ga = ((size_t)(r0 + row) * HIDD + kt) * 2 + (size_t)lc * 16;
        const size_t gb = ((size_t)(c0 + row) * HIDD + kt) * 2 + (size_t)lc * 16;
        const int ld = wid * 4096 + q * 1024;
        stage16((const char*)Xh + ga, pAh + ld);
        stage16((const char*)Xl + ga, pAl + ld);
        stage16((const char*)Xh + gb, pBh + ld);
        stage16((const char*)Xl + gb, pBl + ld);
      }
      __syncthreads();                         // compiler drains vmcnt before barrier
      #pragma unroll
      for (int kk = 0; kk < 2; ++kk) {
        bf16x8 ah[4], al[4], bh[4], bl[4];
        #pragma unroll
        for (int m = 0; m < 4; ++m) {
          const int ar = wr + m * 16 + fr;
          const int off = ar * 128 + (((kk * 4 + fq) ^ (ar & 7)) << 4);
          ah[m] = *(const bf16x8*)(pAh + off);
          al[m] = *(const bf16x8*)(pAl + off);
        }
        #pragma unroll
        for (int n = 0; n < 4; ++n) {
          const int br = wc + n * 16 + fr;
          const int off = br * 128 + (((kk * 4 + fq) ^ (br & 7)) << 4);
          bh[n] = *(const bf16x8*)(pBh + off);
          bl[n] = *(const bf16x8*)(pBl + off);
        }
        #pragma unroll
        for (int m = 0; m < 4; ++m)
          #pragma unroll
          for (int n = 0; n < 4; ++n) {
            acc[m][n] = __builtin_amdgcn_mfma_f32_16x16x32_bf16(ah[m], bh[n], acc[m][n], 0, 0, 0);
            acc[m][n] = __builtin_amdgcn_mfma_f32_16x16x32_bf16(ah[m], bl[n], acc[m][n], 0, 0, 0);
            acc[m][n] = __builtin_amdgcn_mfma_f32_16x16x32_bf16(al[m], bh[n], acc[m][n], 0, 0, 0);
          }
      }
    }
    __syncthreads();                           // all frag reads done; reuse LDS as Ds
    // score = x2[j] - 2*dot; rotate col slot by row so the scan is conflict-free
    #pragma unroll
    for (int n = 0; n < 4; ++n) {
      const int col = wc + n * 16 + fr;
      const float c2 = x2[c0 + col];
      #pragma unroll
      for (int m = 0; m < 4; ++m) {
        #pragma unroll
        for (int j = 0; j < 4; ++j) {
          const int row = wr + m * 16 + fq * 4 + j;
          Ds[row * 128 + ((col + row) & 127)] = c2 - 2.0f * acc[m][n][j];
        }
      }
    }
    __syncthreads();
    if (tid < 128) {
      for (int c = 0; c < 128; ++c) {
        const int p = (c + tid) & 127;
        top5_insert(Ds[tid * 128 + p], c0 + c, d0, d1, d2, d3, d4, i0, i1, i2, i3, i4);
      }
    }
  }
  if (tid < 128) {
    size_t base = ((size_t)(r0 + tid) * NSPLIT + jgrp) * 5;
    pdist[base + 0] = d0; pdist[base + 1] = d1; pdist[base + 2] = d2;
    pdist[base + 3] = d3; pdist[base + 4] = d4;
    pidx[base + 0] = i0; pidx[base + 1] = i1; pidx[base + 2] = i2;
    pidx[base + 3] = i3; pidx[base + 4] = i4;
  }
}

// ---------- merge NSPLIT partial top-5 lists per row -------------------------
__global__ void knn_merge_kernel(const float* __restrict__ pdist,
                                 const int* __restrict__ pidx, int* __restrict__ knn) {
  int i = blockIdx.x * 256 + threadIdx.x;
  if (i >= NN) return;
  float d0 = 3e38f, d1 = 3e38f, d2 = 3e38f, d3 = 3e38f, d4 = 3e38f;
  int i0 = 0, i1 = 0, i2 = 0, i3 = 0, i4 = 0;
  for (int s = 0; s < NSPLIT * 5; ++s) {
    float d = pdist[(size_t)i * NSPLIT * 5 + s];
    int ix = pidx[(size_t)i * NSPLIT * 5 + s];
    top5_insert(d, ix, d0, d1, d2, d3, d4, i0, i1, i2, i3, i4);
  }
  knn[i * 5 + 0] = i0; knn[i * 5 + 1] = i1; knn[i * 5 + 2] = i2;
  knn[i * 5 + 3] = i3; knn[i * 5 + 4] = i4;
}

// ---------- tiled fp32 GEMM: C[M,N] = A[M,K] @ B[N,K]^T + bias[N] ------------
__global__ __launch_bounds__(256) void gemm_nt_bias_kernel(const float* __restrict__ A,
    const float* __restrict__ B, const float* __restrict__ bias, float* __restrict__ C,
    int M, int Nc, int K) {
  __shared__ float As[32][65];
  __shared__ float Bs[32][65];
  int r0 = blockIdx.x * 64, c0 = blockIdx.y * 64;
  int tid = threadIdx.x, tx = tid & 15, ty = tid >> 4;
  float acc[4][4] = {};
  for (int kt = 0; kt < K; kt += 32) {
    #pragma unroll
    for (int l = 0; l < 8; ++l) {
      int idx = l * 256 + tid;
      int m = idx >> 5, k = idx & 31;
      As[k][m] = A[(size_t)(r0 + m) * K + kt + k];
      Bs[k][m] = B[(size_t)(c0 + m) * K + kt + k];
    }
    __syncthreads();
    #pragma unroll
    for (int k = 0; k < 32; ++k) {
      float a[4], b[4];
      #pragma unroll
      for (int i = 0; i < 4; ++i) a[i] = As[k][ty * 4 + i];
      #pragma unroll
      for (int j = 0; j < 4; ++j) b[j] = Bs[k][tx * 4 + j];
      #pragma unroll
      for (int i = 0; i < 4; ++i)
        #pragma unroll
        for (int j = 0; j < 4; ++j) acc[i][j] += a[i] * b[j];
    }
    __syncthreads();
  }
  #pragma unroll
  for (int i = 0; i < 4; ++i) {
    int r = r0 + ty * 4 + i;
    #pragma unroll
    for (int j = 0; j < 4; ++j) {
      int c = c0 + tx * 4 + j;
      C[(size_t)r * Nc + c] = acc[i][j] + bias[c];
    }
  }
}

// ---------- instance GATv2 aggregation over 6 edges + ctx = agg + cmean ------
__global__ __launch_bounds__(256) void inst_gat_kernel(const float* __restrict__ xl,
    const float* __restrict__ xr, const int* __restrict__ knn,
    const float* __restrict__ att, const float* __restrict__ bias,
    const float* __restrict__ cmean, float* __restrict__ ctx) {
  __shared__ float sc[12];
  __shared__ float alpha[12];
  __shared__ int nbr[6];
  const int i = blockIdx.x;
  const int tid = threadIdx.x;
  if (tid < 5) nbr[tid] = knn[i * 5 + tid];
  else if (tid == 5) nbr[5] = i;   // explicit self loop (in addition to knn self)
  __syncthreads();
  int lane = tid & 63, w = tid >> 6;
  for (int t = w; t < 12; t += 4) {
    int e = t >> 1, h = t & 1;
    const float* xlr = xl + (size_t)nbr[e] * OD + h * 256;
    const float* xrr = xr + (size_t)i * OD + h * 256;
    const float* ar  = att + h * 256;
    float s = 0.f;
    #pragma unroll
    for (int q = 0; q < 4; ++q) {
      int d = lane + q * 64;
      float v = xlr[d] + xrr[d];
      v = v > 0.f ? v : NEG * v;
      s += v * ar[d];
    }
    #pragma unroll
    for (int off = 32; off; off >>= 1) s += __shfl_down(s, off);
    if (lane == 0) sc[t] = s;
  }
  __syncthreads();
  if (tid < 2) {
    int h = tid;
    float m = -3e38f;
    #pragma unroll
    for (int e = 0; e < 6; ++e) m = fmaxf(m, sc[e * 2 + h]);
    float ssum = 0.f;
    #pragma unroll
    for (int e = 0; e < 6; ++e) { float ex = expf(sc[e * 2 + h] - m); alpha[e * 2 + h] = ex; ssum += ex; }
    float inv = 1.f / ssum;
    #pragma unroll
    for (int e = 0; e < 6; ++e) alpha[e * 2 + h] *= inv;
  }
  __syncthreads();
  for (int c = tid; c < OD; c += 256) {
    int h = c >> 8;
    float acc = 0.f;
    #pragma unroll
    for (int e = 0; e < 6; ++e) acc += alpha[e * 2 + h] * xl[(size_t)nbr[e] * OD + c];
    ctx[(size_t)i * OD + c] = acc + bias[c] + cmean[c];
  }
}

// ---------- fused epilogue: LN1 -> LN2 -> GELU -> 18-way classifier ----------
__global__ __launch_bounds__(256) void epilogue_kernel(const float* __restrict__ inst,
    const float* __restrict__ attn, const float* __restrict__ g1, const float* __restrict__ b1,
    const float* __restrict__ g2, const float* __restrict__ b2, const float* __restrict__ gw,
    const float* __restrict__ gb, const float* __restrict__ temp, float* __restrict__ out) {
  __shared__ float buf[HIDD];
  __shared__ float red[4];
  const int i = blockIdx.x;
  const int tid = threadIdx.x;
  const int lane = tid & 63, w = tid >> 6;
  size_t base = (size_t)i * HIDD;
  float v0 = inst[base + tid]       + attn[base + tid];
  float v1 = inst[base + tid + 256] + attn[base + tid + 256];
  float v2 = inst[base + tid + 512] + attn[base + tid + 512];

  float s = v0 + v1 + v2;
  #pragma unroll
  for (int off = 32; off; off >>= 1) s += __shfl_down(s, off);
  if (lane == 0) red[w] = s;
  __syncthreads();
  float mean = (red[0] + red[1] + red[2] + red[3]) * (1.f / HIDD);
  __syncthreads();
  float e0 = v0 - mean, e1 = v1 - mean, e2 = v2 - mean;
  s = e0 * e0 + e1 * e1 + e2 * e2;
  #pragma unroll
  for (int off = 32; off; off >>= 1) s += __shfl_down(s, off);
  if (lane == 0) red[w] = s;
  __syncthreads();
  float rstd = rsqrtf((red[0] + red[1] + red[2] + red[3]) * (1.f / HIDD) + LN_EPS);
  __syncthreads();
  float y0 = e0 * rstd * g1[tid]       + b1[tid];
  float y1 = e1 * rstd * g1[tid + 256] + b1[tid + 256];
  float y2 = e2 * rstd * g1[tid + 512] + b1[tid + 512];

  s = y0 + y1 + y2;
  #pragma unroll
  for (int off = 32; off; off >>= 1) s += __shfl_down(s, off);
  if (lane == 0) red[w] = s;
  __syncthreads();
  float mean2 = (red[0] + red[1] + red[2] + red[3]) * (1.f / HIDD);
  __syncthreads();
  float f0 = y0 - mean2, f1 = y1 - mean2, f2 = y2 - mean2;
  s = f0 * f0 + f1 * f1 + f2 * f2;
  #pragma unroll
  for (int off = 32; off; off >>= 1) s += __shfl_down(s, off);
  if (lane == 0) red[w] = s;
  __syncthreads();
  float rstd2 = rsqrtf((red[0] + red[1] + red[2] + red[3]) * (1.f / HIDD) + LN_EPS);
  float z0 = f0 * rstd2 * g2[tid]       + b2[tid];
  float z1 = f1 * rstd2 * g2[tid + 256] + b2[tid + 256];
  float z2 = f2 * rstd2 * g2[tid + 512] + b2[tid + 512];
  buf[tid]       = 0.5f * z0 * (1.f + erff(z0 * 0.70710678118654752f));
  buf[tid + 256] = 0.5f * z1 * (1.f + erff(z1 * 0.70710678118654752f));
  buf[tid + 512] = 0.5f * z2 * (1.f + erff(z2 * 0.70710678118654752f));
  __syncthreads();

  float invT = 1.f / temp[0];
  for (int c = w; c < NCLS; c += 4) {
    const float* wr = gw + (size_t)c * HIDD;
    float acc = 0.f;
    for (int d = lane; d < HIDD; d += 64) acc += buf[d] * wr[d];
    #pragma unroll
    for (int off = 32; off; off >>= 1) acc += __shfl_down(acc, off);
    if (lane == 0) out[(size_t)i * NCLS + c] = (acc + gb[c]) * invT;
  }
}

// ---------------------------------------------------------------------------
extern "C" void kernel_launch(void* const* d_in, const int* in_sizes, int n_in,
                              void* d_out, int out_size, void* d_ws, size_t ws_size,
                              hipStream_t stream) {
  (void)in_sizes; (void)n_in; (void)out_size; (void)ws_size;
  const float* X       = (const float*)d_in[0];
  const int*   cei     = (const int*)  d_in[1];
  const float* cemb    = (const float*)d_in[2];
  const float* gc_wl   = (const float*)d_in[3];
  const float* gc_bl   = (const float*)d_in[4];
  const float* gc_wr   = (const float*)d_in[5];
  const float* gc_br   = (const float*)d_in[6];
  const float* gc_att  = (const float*)d_in[7];
  const float* gc_bias = (const float*)d_in[8];
  const float* gi_wl   = (const float*)d_in[9];
  const float* gi_bl   = (const float*)d_in[10];
  const float* gi_wr   = (const float*)d_in[11];
  const float* gi_br   = (const float*)d_in[12];
  const float* gi_att  = (const float*)d_in[13];
  const float* gi_bias = (const float*)d_in[14];
  // d_in[15]=q_w, d_in[16]=q_b: cancel out of the forward value (seq_len 1)
  const float* ctx_w   = (const float*)d_in[17];
  const float* ctx_b   = (const float*)d_in[18];
  const float* wv      = (const float*)d_in[19];
  const float* bv      = (const float*)d_in[20];
  const float* wo      = (const float*)d_in[21];
  const float* bo      = (const float*)d_in[22];
  const float* ln1_g   = (const float*)d_in[23];
  const float* ln1_b   = (const float*)d_in[24];
  const float* ln2_g   = (const float*)d_in[25];
  const float* ln2_b   = (const float*)d_in[26];
  const float* gw_w    = (const float*)d_in[27];
  const float* gw_b    = (const float*)d_in[28];
  const float* temp    = (const float*)d_in[29];
  float* out = (float*)d_out;

  // workspace layout (floats)
  float* ws    = (float*)d_ws;
  float* xl    = ws;                               // 8192*512 f32
  float* xr    = xl + (size_t)NN * OD;             // 8192*512 f32
  float* ctx   = xr + (size_t)NN * OD;             // 8192*512 f32
  float* x2    = ctx + (size_t)NN * OD;            // 8192
  float* pdist = x2 + NN;                          // 8192*NSPLIT*5
  int*   pidx  = (int*)(pdist + (size_t)NN * NSPLIT * 5);
  int*   knn   = pidx + (size_t)NN * NSPLIT * 5;   // 8192*5
  float* xlc   = (float*)(knn + NN * 5);           // 18*512
  float* xrc   = xlc + NCLS * OD;                  // 18*512
  float* cmean = xrc + NCLS * OD;                  // 512
  float* T1    = cmean + OD;                       // 768*512
  float* W3    = T1 + (size_t)HIDD * OD;           // 768*512
  float* t1b   = W3 + (size_t)HIDD * OD;           // 768
  float* bp    = t1b + HIDD;                       // 768
  // bf16 split of X aliases xl/xr (12.6MB each <= 16.8MB; xl/xr written later)
  ushort* Xhs  = (ushort*)xl;
  ushort* Xls  = (ushort*)xr;
  float* attnb = xl;  // alias: attn [8192,768] overlays xl+xr (dead by then)

  // --- class path -> cmean[512] ---
  small_lin_kernel<<<(NCLS * OD + 255) / 256, 256, 0, stream>>>(cemb, gc_wl, gc_bl, xlc, NCLS, HIDD, OD);
  small_lin_kernel<<<(NCLS * OD + 255) / 256, 256, 0, stream>>>(cemb, gc_wr, gc_br, xrc, NCLS, HIDD, OD);
  class_gat_kernel<<<1, 256, 0, stream>>>(cei, xlc, xrc, gc_att, gc_bias, cmean);

  // --- kNN graph (MFMA split-bf16 distances) ---
  split_kernel<<<(NN * HIDD / 4) / 256, 256, 0, stream>>>(X, Xhs, Xls);
  rownorm_kernel<<<NN / 4, 256, 0, stream>>>(X, x2);
  dist_topk_mfma<<<dim3(NN / 128, NSPLIT), 256, 0, stream>>>(Xhs, Xls, x2, pdist, pidx);
  knn_merge_kernel<<<NN / 256, 256, 0, stream>>>(pdist, pidx, knn);

  // --- instance GATv2 ---
  gemm_nt_bias_kernel<<<dim3(NN / 64, OD / 64), 256, 0, stream>>>(X, gi_wl, gi_bl, xl, NN, OD, HIDD);
  gemm_nt_bias_kernel<<<dim3(NN / 64, OD / 64), 256, 0, stream>>>(X, gi_wr, gi_br, xr, NN, OD, HIDD);
  inst_gat_kernel<<<NN, 256, 0, stream>>>(xl, xr, knn, gi_att, gi_bias, cmean, ctx);

  // --- fold attention chain: attn = ctx @ (wo@wv@ctx_w)^T + b' ---
  small_nn_kernel<<<(HIDD * OD + 255) / 256, 256, 0, stream>>>(wv, ctx_w, T1, HIDD, HIDD, OD);
  small_nn_kernel<<<(HIDD * OD + 255) / 256, 256, 0, stream>>>(wo, T1, W3, HIDD, HIDD, OD);
  small_lin_kernel<<<(HIDD + 255) / 256, 256, 0, stream>>>(ctx_b, wv, bv, t1b, 1, HIDD, HIDD);
  small_lin_kernel<<<(HIDD + 255) / 256, 256, 0, stream>>>(t1b, wo, bo, bp, 1, HIDD, HIDD);
  gemm_nt_bias_kernel<<<dim3(NN / 64, HIDD / 64), 256, 0, stream>>>(ctx, W3, bp, attnb, NN, HIDD, OD);

  // --- LN -> LN -> GELU -> classifier ---
  epilogue_kernel<<<NN, 256, 0, stream>>>(X, attnb, ln1_g, ln1_b, ln2_g, ln2_b, gw_w, gw_b, temp, out);
}

// Round 4
// 2031.672 us; speedup vs baseline: 1.9388x; 1.2066x over previous
//
#include <hip/hip_runtime.h>
#include <hip/hip_bf16.h>
#include <hip/hip_fp16.h>
#include <math.h>

#define NN 8192
#define HIDD 768
#define NCLS 18
#define OD 512          // HEADS*GD = 2*256
#define ETOT 342        // 324 class edges + 18 self loops
#define NGRP 16         // column groups for dist kernel
#define NEG 0.2f
#define LN_EPS 1e-5f

typedef __attribute__((ext_vector_type(8))) short bf16x8;
typedef __attribute__((ext_vector_type(4))) float f32x4;

// ---------- sorted top-5 insert (static indices, stays in registers) --------
__device__ __forceinline__ void top5_insert(float s, int idx,
    float& d0, float& d1, float& d2, float& d3, float& d4,
    int& i0, int& i1, int& i2, int& i3, int& i4) {
  if (s >= d4) return;
  if (s < d3) {
    d4 = d3; i4 = i3;
    if (s < d2) {
      d3 = d2; i3 = i2;
      if (s < d1) {
        d2 = d1; i2 = i1;
        if (s < d0) { d1 = d0; i1 = i0; d0 = s; i0 = idx; }
        else        { d1 = s;  i1 = idx; }
      } else { d2 = s; i2 = idx; }
    } else { d3 = s; i3 = idx; }
  } else { d4 = s; i4 = idx; }
}

// ---------- top-8 insert, rank-based so every reg index is static ----------
__device__ __forceinline__ void top8_insert(float s, int idx,
                                            float (&dd)[8], int (&ci)[8]) {
  if (s >= dd[7]) return;
  int rank = 0;
  #pragma unroll
  for (int k = 0; k < 7; ++k) rank += (s >= dd[k]) ? 1 : 0;
  #pragma unroll
  for (int k = 7; k >= 1; --k) {
    if (k > rank) { dd[k] = dd[k-1]; ci[k] = ci[k-1]; }
  }
  #pragma unroll
  for (int k = 0; k < 8; ++k) {
    if (k == rank) { dd[k] = s; ci[k] = idx; }
  }
}

// ---------- async global->LDS 16B (used only in gemm_nt_mfma) ---------------
__device__ __forceinline__ void stage16(const void* g, void* l) {
  __builtin_amdgcn_global_load_lds(
      (const __attribute__((address_space(1))) unsigned int*)g,
      (__attribute__((address_space(3))) unsigned int*)l, 16, 0, 0);
}

// ---------- fp32 -> bf16 (rte) ----------------------------------------------
__global__ __launch_bounds__(256) void tobf16_kernel(const float* __restrict__ src,
    ushort* __restrict__ dst, int n4) {
  int i = blockIdx.x * 256 + threadIdx.x;
  if (i >= n4) return;
  float4 v = ((const float4*)src)[i];
  float vv[4] = {v.x, v.y, v.z, v.w};
  ushort h[4];
  #pragma unroll
  for (int j = 0; j < 4; ++j) {
    __hip_bfloat16 b = __float2bfloat16(vv[j]);
    h[j] = *(ushort*)&b;
  }
  ((ushort4*)dst)[i] = make_ushort4(h[0], h[1], h[2], h[3]);
}

// ---------- row squared norms ------------------------------------------------
__global__ __launch_bounds__(256) void rownorm_kernel(const float* __restrict__ X,
                                                      float* __restrict__ x2) {
  int row = blockIdx.x * 4 + (threadIdx.x >> 6);
  int lane = threadIdx.x & 63;
  const float* xr = X + (size_t)row * HIDD;
  float s = 0.f;
  for (int k = lane; k < HIDD; k += 64) { float v = xr[k]; s += v * v; }
  #pragma unroll
  for (int off = 32; off; off >>= 1) s += __shfl_down(s, off);
  if (lane == 0) x2[row] = s;
}

// ---------- small Y = X @ W^T + b (thread per output) ------------------------
__global__ void small_lin_kernel(const float* __restrict__ X, const float* __restrict__ W,
                                 const float* __restrict__ b, float* __restrict__ Y,
                                 int n, int K, int O) {
  int idx = blockIdx.x * 256 + threadIdx.x;
  if (idx >= n * O) return;
  int row = idx / O, o = idx - row * O;
  const float* xr = X + (size_t)row * K;
  const float* wr = W + (size_t)o * K;
  float acc = 0.f;
  for (int k = 0; k < K; ++k) acc += xr[k] * wr[k];
  Y[idx] = acc + b[o];
}

// ---------- small C = A @ B (thread per output) ------------------------------
__global__ void small_nn_kernel(const float* __restrict__ A, const float* __restrict__ B,
                                float* __restrict__ C, int M, int K, int Nc) {
  int idx = blockIdx.x * 256 + threadIdx.x;
  if (idx >= M * Nc) return;
  int i = idx / Nc, j = idx - i * Nc;
  float acc = 0.f;
  for (int k = 0; k < K; ++k) acc += A[(size_t)i * K + k] * B[(size_t)k * Nc + j];
  C[idx] = acc;
}

// ---------- class-graph GATv2 -> mean over nodes (single block) --------------
__global__ __launch_bounds__(256) void class_gat_kernel(const int* __restrict__ ei,
    const float* __restrict__ xlc, const float* __restrict__ xrc,
    const float* __restrict__ att, const float* __restrict__ bias,
    float* __restrict__ cmean) {
  __shared__ float sc[ETOT * 2];
  __shared__ int es[ETOT], ed[ETOT];
  __shared__ float mx[NCLS][2], sm[NCLS][2];
  int tid = threadIdx.x;
  for (int e = tid; e < ETOT; e += 256) {
    if (e < 324) { es[e] = ei[e]; ed[e] = ei[324 + e]; }
    else         { es[e] = e - 324; ed[e] = e - 324; }
  }
  __syncthreads();
  int lane = tid & 63, w = tid >> 6;
  for (int t = w; t < ETOT * 2; t += 4) {
    int e = t >> 1, h = t & 1;
    const float* xlr = xlc + (size_t)es[e] * OD + h * 256;
    const float* xrr = xrc + (size_t)ed[e] * OD + h * 256;
    const float* ar  = att + h * 256;
    float s = 0.f;
    for (int d = lane; d < 256; d += 64) {
      float v = xlr[d] + xrr[d];
      v = v > 0.f ? v : NEG * v;
      s += v * ar[d];
    }
    #pragma unroll
    for (int off = 32; off; off >>= 1) s += __shfl_down(s, off);
    if (lane == 0) sc[t] = s;
  }
  __syncthreads();
  if (tid < NCLS * 2) {
    int d = tid >> 1, h = tid & 1;
    float m = -3e38f;
    for (int e = 0; e < ETOT; ++e) if (ed[e] == d) m = fmaxf(m, sc[e * 2 + h]);
    float ssum = 0.f;
    for (int e = 0; e < ETOT; ++e) if (ed[e] == d) ssum += expf(sc[e * 2 + h] - m);
    mx[d][h] = m; sm[d][h] = 1.f / ssum;
  }
  __syncthreads();
  for (int t = tid; t < ETOT * 2; t += 256) {
    int e = t >> 1, h = t & 1;
    sc[t] = expf(sc[t] - mx[ed[e]][h]) * sm[ed[e]][h];
  }
  __syncthreads();
  for (int c = tid; c < OD; c += 256) {
    int h = c >> 8;
    float acc = 0.f;
    for (int e = 0; e < ETOT; ++e) acc += sc[e * 2 + h] * xlc[(size_t)es[e] * OD + c];
    cmean[c] = acc * (1.f / 18.f) + bias[c];
  }
}

// ---------- stage 1: bf16 MFMA distances + per-row approx top-8 --------------
// 128x128 tile / block (4 waves of 64x64), BK=64, cols split into NGRP groups.
// Derisked: reg-staged LDS (no global_load_lds here), NO LDS unions, no
// cross-wave merge (one thread owns one row's scan).
__global__ __launch_bounds__(256) void dist_topk_mfma(
    const ushort* __restrict__ Xh, const float* __restrict__ x2,
    float* __restrict__ pcd, int* __restrict__ pci) {
  __shared__ char sA[16384];            // A staging [128 rows][8 chunks of 16B], swizzled
  __shared__ char sB[16384];            // B staging
  __shared__ __half Dh[128 * 128];      // score tile (separate buffer, no union)
  __shared__ float c2s[128];

  const int tid = threadIdx.x;
  const int lane = tid & 63, wid = tid >> 6;
  const int fr = lane & 15, fq = lane >> 4;
  const int r0 = blockIdx.x * 128;
  const int grp = blockIdx.y;
  const int wr = (wid >> 1) * 64, wc = (wid & 1) * 64;

  float dd[8]; int ci[8];
  #pragma unroll
  for (int k = 0; k < 8; ++k) { dd[k] = 3e38f; ci[k] = 0; }

  for (int jt = 0; jt < (NN / NGRP) / 128; ++jt) {
    const int c0 = grp * (NN / NGRP) + jt * 128;
    __syncthreads();                         // prev scan done (c2s free)
    if (tid < 128) c2s[tid] = x2[c0 + tid];
    f32x4 acc[4][4] = {};
    for (int kt = 0; kt < HIDD; kt += 64) {
      __syncthreads();                       // frag reads of prev kt done
      // reg-staged: load bf16x8 from global, ds_write to swizzled slot.
      // write swizzle (chunk ^ row&7) matches the read swizzle below (rule #21).
      #pragma unroll
      for (int q = 0; q < 4; ++q) {
        const int chunkid = q * 256 + tid;
        const int row = chunkid >> 3, cc = chunkid & 7;
        const bf16x8 va = *(const bf16x8*)(Xh + (size_t)(r0 + row) * HIDD + kt + cc * 8);
        const bf16x8 vb = *(const bf16x8*)(Xh + (size_t)(c0 + row) * HIDD + kt + cc * 8);
        const int wi = row * 128 + ((cc ^ (row & 7)) << 4);
        *(bf16x8*)(sA + wi) = va;
        *(bf16x8*)(sB + wi) = vb;
      }
      __syncthreads();                       // staged data visible
      #pragma unroll
      for (int kk = 0; kk < 2; ++kk) {
        bf16x8 ah[4], bh[4];
        #pragma unroll
        for (int m = 0; m < 4; ++m) {
          const int ar = wr + m * 16 + fr;
          const int off = ar * 128 + (((kk * 4 + fq) ^ (ar & 7)) << 4);
          ah[m] = *(const bf16x8*)(sA + off);
        }
        #pragma unroll
        for (int n = 0; n < 4; ++n) {
          const int br = wc + n * 16 + fr;
          const int off = br * 128 + (((kk * 4 + fq) ^ (br & 7)) << 4);
          bh[n] = *(const bf16x8*)(sB + off);
        }
        #pragma unroll
        for (int m = 0; m < 4; ++m)
          #pragma unroll
          for (int n = 0; n < 4; ++n)
            acc[m][n] = __builtin_amdgcn_mfma_f32_16x16x32_bf16(ah[m], bh[n], acc[m][n], 0, 0, 0);
      }
    }
    __syncthreads();                         // all frag reads done
    // store -2*dot as f16 into the dedicated tile, col slot rotated by row
    #pragma unroll
    for (int n = 0; n < 4; ++n) {
      const int col = wc + n * 16 + fr;
      #pragma unroll
      for (int m = 0; m < 4; ++m) {
        #pragma unroll
        for (int j = 0; j < 4; ++j) {
          const int row = wr + m * 16 + fq * 4 + j;
          Dh[row * 128 + ((col + row) & 127)] = __float2half(-2.0f * acc[m][n][j]);
        }
      }
    }
    __syncthreads();
    // scan: one thread per row, full 128 cols, running top-8 across tiles
    if (tid < 128) {
      const int r = tid;
      for (int c = 0; c < 128; ++c) {
        const float s = c2s[c] + __half2float(Dh[r * 128 + ((c + r) & 127)]);
        top8_insert(s, c0 + c, dd, ci);
      }
    }
  }
  if (tid < 128) {
    const size_t base = ((size_t)(r0 + tid) * NGRP + grp) * 8;
    #pragma unroll
    for (int k = 0; k < 8; ++k) { pcd[base + k] = dd[k]; pci[base + k] = ci[k]; }
  }
}

// ---------- merge NGRP approx top-8 lists -> per-row top-8 candidates --------
__global__ __launch_bounds__(256) void cand_merge_kernel(const float* __restrict__ pcd,
    const int* __restrict__ pci, int* __restrict__ cand) {
  const int row = blockIdx.x * 256 + threadIdx.x;
  if (row >= NN) return;
  float dd[8]; int ci[8];
  #pragma unroll
  for (int k = 0; k < 8; ++k) { dd[k] = 3e38f; ci[k] = 0; }
  for (int g = 0; g < NGRP; ++g) {
    const size_t base = ((size_t)row * NGRP + g) * 8;
    #pragma unroll
    for (int k = 0; k < 8; ++k) top8_insert(pcd[base + k], pci[base + k], dd, ci);
  }
  #pragma unroll
  for (int k = 0; k < 8; ++k) cand[row * 8 + k] = ci[k];
}

// ---------- stage 2: exact fp32 refine of 8 candidates -> exact top-5 --------
__global__ __launch_bounds__(256) void refine_kernel(const float* __restrict__ X,
    const float* __restrict__ x2, const int* __restrict__ cand, int* __restrict__ knn) {
  const int row = blockIdx.x * 4 + (threadIdx.x >> 6);
  const int lane = threadIdx.x & 63;
  int c[8];
  #pragma unroll
  for (int k = 0; k < 8; ++k) c[k] = cand[row * 8 + k];
  const float* xi = X + (size_t)row * HIDD;
  float acc[8] = {};
  for (int d = lane; d < HIDD; d += 64) {
    const float a = xi[d];
    #pragma unroll
    for (int k = 0; k < 8; ++k) acc[k] += a * X[(size_t)c[k] * HIDD + d];
  }
  #pragma unroll
  for (int k = 0; k < 8; ++k) {
    #pragma unroll
    for (int off = 32; off; off >>= 1) acc[k] += __shfl_down(acc[k], off);
  }
  if (lane == 0) {
    float d0 = 3e38f, d1 = 3e38f, d2 = 3e38f, d3 = 3e38f, d4 = 3e38f;
    int i0 = 0, i1 = 0, i2 = 0, i3 = 0, i4 = 0;
    #pragma unroll
    for (int k = 0; k < 8; ++k) {
      const float s = x2[c[k]] - 2.0f * acc[k];
      top5_insert(s, c[k], d0, d1, d2, d3, d4, i0, i1, i2, i3, i4);
    }
    knn[row * 5 + 0] = i0; knn[row * 5 + 1] = i1; knn[row * 5 + 2] = i2;
    knn[row * 5 + 3] = i3; knn[row * 5 + 4] = i4;
  }
}

// ---------- bf16 MFMA GEMM: C[8192,Nc] = A @ B^T + bias ----------------------
__global__ __launch_bounds__(256) void gemm_nt_mfma(const ushort* __restrict__ A,
    const ushort* __restrict__ B, const float* __restrict__ bias,
    float* __restrict__ C, int Nc, int K) {
  __shared__ char lds[32768];
  char* const pA = lds;
  char* const pB = lds + 16384;
  const int tid = threadIdx.x;
  const int lane = tid & 63, wid = tid >> 6;
  const int fr = lane & 15, fq = lane >> 4;
  const int r0 = blockIdx.x * 128;
  const int c0 = blockIdx.y * 128;
  const int wr = (wid >> 1) * 64, wc = (wid & 1) * 64;
  f32x4 acc[4][4] = {};
  for (int kt = 0; kt < K; kt += 64) {
    __syncthreads();
    #pragma unroll
    for (int q = 0; q < 4; ++q) {
      const int chunk = wid * 256 + q * 64 + lane;
      const int row = chunk >> 3;
      const int lc = (chunk & 7) ^ (row & 7);
      const int ld = wid * 4096 + q * 1024;
      stage16((const char*)A + ((size_t)(r0 + row) * K + kt) * 2 + (size_t)lc * 16, pA + ld);
      stage16((const char*)B + ((size_t)(c0 + row) * K + kt) * 2 + (size_t)lc * 16, pB + ld);
    }
    __syncthreads();
    #pragma unroll
    for (int kk = 0; kk < 2; ++kk) {
      bf16x8 ah[4], bh[4];
      #pragma unroll
      for (int m = 0; m < 4; ++m) {
        const int ar = wr + m * 16 + fr;
        const int off = ar * 128 + (((kk * 4 + fq) ^ (ar & 7)) << 4);
        ah[m] = *(const bf16x8*)(pA + off);
      }
      #pragma unroll
      for (int n = 0; n < 4; ++n) {
        const int br = wc + n * 16 + fr;
        const int off = br * 128 + (((kk * 4 + fq) ^ (br & 7)) << 4);
        bh[n] = *(const bf16x8*)(pB + off);
      }
      #pragma unroll
      for (int m = 0; m < 4; ++m)
        #pragma unroll
        for (int n = 0; n < 4; ++n)
          acc[m][n] = __builtin_amdgcn_mfma_f32_16x16x32_bf16(ah[m], bh[n], acc[m][n], 0, 0, 0);
    }
  }
  #pragma unroll
  for (int n = 0; n < 4; ++n) {
    const int cc = c0 + wc + n * 16 + fr;
    const float bs = bias[cc];
    #pragma unroll
    for (int m = 0; m < 4; ++m) {
      #pragma unroll
      for (int j = 0; j < 4; ++j) {
        const int rr = r0 + wr + m * 16 + fq * 4 + j;
        C[(size_t)rr * Nc + cc] = acc[m][n][j] + bs;
      }
    }
  }
}

// ---------- instance GATv2 aggregation over 6 edges + ctx = agg + cmean ------
__global__ __launch_bounds__(256) void inst_gat_kernel(const float* __restrict__ xl,
    const float* __restrict__ xr, const int* __restrict__ knn,
    const float* __restrict__ att, const float* __restrict__ bias,
    const float* __restrict__ cmean, float* __restrict__ ctx) {
  __shared__ float sc[12];
  __shared__ float alpha[12];
  __shared__ int nbr[6];
  const int i = blockIdx.x;
  const int tid = threadIdx.x;
  if (tid < 5) nbr[tid] = knn[i * 5 + tid];
  else if (tid == 5) nbr[5] = i;   // explicit self loop (in addition to knn self)
  __syncthreads();
  int lane = tid & 63, w = tid >> 6;
  for (int t = w; t < 12; t += 4) {
    int e = t >> 1, h = t & 1;
    const float* xlr = xl + (size_t)nbr[e] * OD + h * 256;
    const float* xrr = xr + (size_t)i * OD + h * 256;
    const float* ar  = att + h * 256;
    float s = 0.f;
    #pragma unroll
    for (int q = 0; q < 4; ++q) {
      int d = lane + q * 64;
      float v = xlr[d] + xrr[d];
      v = v > 0.f ? v : NEG * v;
      s += v * ar[d];
    }
    #pragma unroll
    for (int off = 32; off; off >>= 1) s += __shfl_down(s, off);
    if (lane == 0) sc[t] = s;
  }
  __syncthreads();
  if (tid < 2) {
    int h = tid;
    float m = -3e38f;
    #pragma unroll
    for (int e = 0; e < 6; ++e) m = fmaxf(m, sc[e * 2 + h]);
    float ssum = 0.f;
    #pragma unroll
    for (int e = 0; e < 6; ++e) { float ex = expf(sc[e * 2 + h] - m); alpha[e * 2 + h] = ex; ssum += ex; }
    float inv = 1.f / ssum;
    #pragma unroll
    for (int e = 0; e < 6; ++e) alpha[e * 2 + h] *= inv;
  }
  __syncthreads();
  for (int c = tid; c < OD; c += 256) {
    int h = c >> 8;
    float acc = 0.f;
    #pragma unroll
    for (int e = 0; e < 6; ++e) acc += alpha[e * 2 + h] * xl[(size_t)nbr[e] * OD + c];
    ctx[(size_t)i * OD + c] = acc + bias[c] + cmean[c];
  }
}

// ---------- fused epilogue: LN1 -> LN2 -> GELU -> 18-way classifier ----------
__global__ __launch_bounds__(256) void epilogue_kernel(const float* __restrict__ inst,
    const float* __restrict__ attn, const float* __restrict__ g1, const float* __restrict__ b1,
    const float* __restrict__ g2, const float* __restrict__ b2, const float* __restrict__ gw,
    const float* __restrict__ gb, const float* __restrict__ temp, float* __restrict__ out) {
  __shared__ float buf[HIDD];
  __shared__ float red[4];
  const int i = blockIdx.x;
  const int tid = threadIdx.x;
  const int lane = tid & 63, w = tid >> 6;
  size_t base = (size_t)i * HIDD;
  float v0 = inst[base + tid]       + attn[base + tid];
  float v1 = inst[base + tid + 256] + attn[base + tid + 256];
  float v2 = inst[base + tid + 512] + attn[base + tid + 512];

  float s = v0 + v1 + v2;
  #pragma unroll
  for (int off = 32; off; off >>= 1) s += __shfl_down(s, off);
  if (lane == 0) red[w] = s;
  __syncthreads();
  float mean = (red[0] + red[1] + red[2] + red[3]) * (1.f / HIDD);
  __syncthreads();
  float e0 = v0 - mean, e1 = v1 - mean, e2 = v2 - mean;
  s = e0 * e0 + e1 * e1 + e2 * e2;
  #pragma unroll
  for (int off = 32; off; off >>= 1) s += __shfl_down(s, off);
  if (lane == 0) red[w] = s;
  __syncthreads();
  float rstd = rsqrtf((red[0] + red[1] + red[2] + red[3]) * (1.f / HIDD) + LN_EPS);
  __syncthreads();
  float y0 = e0 * rstd * g1[tid]       + b1[tid];
  float y1 = e1 * rstd * g1[tid + 256] + b1[tid + 256];
  float y2 = e2 * rstd * g1[tid + 512] + b1[tid + 512];

  s = y0 + y1 + y2;
  #pragma unroll
  for (int off = 32; off; off >>= 1) s += __shfl_down(s, off);
  if (lane == 0) red[w] = s;
  __syncthreads();
  float mean2 = (red[0] + red[1] + red[2] + red[3]) * (1.f / HIDD);
  __syncthreads();
  float f0 = y0 - mean2, f1 = y1 - mean2, f2 = y2 - mean2;
  s = f0 * f0 + f1 * f1 + f2 * f2;
  #pragma unroll
  for (int off = 32; off; off >>= 1) s += __shfl_down(s, off);
  if (lane == 0) red[w] = s;
  __syncthreads();
  float rstd2 = rsqrtf((red[0] + red[1] + red[2] + red[3]) * (1.f / HIDD) + LN_EPS);
  float z0 = f0 * rstd2 * g2[tid]       + b2[tid];
  float z1 = f1 * rstd2 * g2[tid + 256] + b2[tid + 256];
  float z2 = f2 * rstd2 * g2[tid + 512] + b2[tid + 512];
  buf[tid]       = 0.5f * z0 * (1.f + erff(z0 * 0.70710678118654752f));
  buf[tid + 256] = 0.5f * z1 * (1.f + erff(z1 * 0.70710678118654752f));
  buf[tid + 512] = 0.5f * z2 * (1.f + erff(z2 * 0.70710678118654752f));
  __syncthreads();

  float invT = 1.f / temp[0];
  for (int c = w; c < NCLS; c += 4) {
    const float* wr = gw + (size_t)c * HIDD;
    float acc = 0.f;
    for (int d = lane; d < HIDD; d += 64) acc += buf[d] * wr[d];
    #pragma unroll
    for (int off = 32; off; off >>= 1) acc += __shfl_down(acc, off);
    if (lane == 0) out[(size_t)i * NCLS + c] = (acc + gb[c]) * invT;
  }
}

// ---------------------------------------------------------------------------
extern "C" void kernel_launch(void* const* d_in, const int* in_sizes, int n_in,
                              void* d_out, int out_size, void* d_ws, size_t ws_size,
                              hipStream_t stream) {
  (void)in_sizes; (void)n_in; (void)out_size; (void)ws_size;
  const float* X       = (const float*)d_in[0];
  const int*   cei     = (const int*)  d_in[1];
  const float* cemb    = (const float*)d_in[2];
  const float* gc_wl   = (const float*)d_in[3];
  const float* gc_bl   = (const float*)d_in[4];
  const float* gc_wr   = (const float*)d_in[5];
  const float* gc_br   = (const float*)d_in[6];
  const float* gc_att  = (const float*)d_in[7];
  const float* gc_bias = (const float*)d_in[8];
  const float* gi_wl   = (const float*)d_in[9];
  const float* gi_bl   = (const float*)d_in[10];
  const float* gi_wr   = (const float*)d_in[11];
  const float* gi_br   = (const float*)d_in[12];
  const float* gi_att  = (const float*)d_in[13];
  const float* gi_bias = (const float*)d_in[14];
  // d_in[15]=q_w, d_in[16]=q_b: cancel out of the forward value (seq_len 1)
  const float* ctx_w   = (const float*)d_in[17];
  const float* ctx_b   = (const float*)d_in[18];
  const float* wv      = (const float*)d_in[19];
  const float* bv      = (const float*)d_in[20];
  const float* wo      = (const float*)d_in[21];
  const float* bo      = (const float*)d_in[22];
  const float* ln1_g   = (const float*)d_in[23];
  const float* ln1_b   = (const float*)d_in[24];
  const float* ln2_g   = (const float*)d_in[25];
  const float* ln2_b   = (const float*)d_in[26];
  const float* gw_w    = (const float*)d_in[27];
  const float* gw_b    = (const float*)d_in[28];
  const float* temp    = (const float*)d_in[29];
  float* out = (float*)d_out;

  // ---- workspace layout (f32 units). R1,R2,R3 are 4.19M f32 each. ----
  // Liveness audit (write-before-read on every call, poison-robust):
  //   R1: pcd/pci (dist->cand_merge) -> xl (gemm->inst_gat) -> ctxh (tobf16->attn gemm)
  //   R2: T1 (small_nn->small_nn) -> xr (gemm->inst_gat) -> attnb head (gemm->epilogue)
  //   R3: Xh+wlh+wrh (tobf16->dist/gemms) -> ctx (inst_gat->tobf16) -> attnb tail
  //   R4: x2, W3, w3h, t1b, bp, cand, knn, xlc, xrc, cmean (no overlays)
  float* ws  = (float*)d_ws;
  float* R1  = ws;
  float* R2  = R1 + (size_t)NN * OD;
  float* R3  = R2 + (size_t)NN * OD;
  float* R4  = R3 + (size_t)NN * OD;

  // R4 sublayout
  float* x2    = R4;                                   // 8192
  float* W3    = x2 + NN;                              // 768*512 f32
  ushort* w3h  = (ushort*)(W3 + (size_t)HIDD * OD);    // 768*512 bf16
  float* t1b   = (float*)(w3h + (size_t)HIDD * OD);    // 768
  float* bp    = t1b + HIDD;                           // 768
  int*   cand  = (int*)(bp + HIDD);                    // 8192*8
  int*   knn   = cand + NN * 8;                        // 8192*5
  float* xlc   = (float*)(knn + NN * 5);               // 18*512
  float* xrc   = xlc + NCLS * OD;                      // 18*512
  float* cmean = xrc + NCLS * OD;                      // 512

  // aliases
  float* xl    = R1;
  float* pcd   = R1;                                   // 8192*16*8 f32
  int*   pci   = (int*)(pcd + (size_t)NN * NGRP * 8);  // 8192*16*8 int
  ushort* ctxh = (ushort*)R1;                          // 8192*512 bf16 (after xl dead)
  float* xr    = R2;
  float* T1    = R2;                                   // 768*512 f32 (dead before xr)
  float* ctx   = R3;
  ushort* Xh   = (ushort*)R3;                          // 8192*768 bf16 (dead before ctx)
  ushort* wlh  = (ushort*)(R3 + (size_t)NN * HIDD / 2);          // 512*768 bf16
  ushort* wrh  = wlh + (size_t)OD * HIDD;                        // 512*768 bf16
  float* attnb = R2;   // 8192*768 f32, spans R2 and first half of R3 (both dead)

  // --- class path -> cmean[512] (independent) ---
  small_lin_kernel<<<(NCLS * OD + 255) / 256, 256, 0, stream>>>(cemb, gc_wl, gc_bl, xlc, NCLS, HIDD, OD);
  small_lin_kernel<<<(NCLS * OD + 255) / 256, 256, 0, stream>>>(cemb, gc_wr, gc_br, xrc, NCLS, HIDD, OD);
  class_gat_kernel<<<1, 256, 0, stream>>>(cei, xlc, xrc, gc_att, gc_bias, cmean);

  // --- fold attention weights: W3 = wo @ wv @ ctx_w, bp = wo@(wv@ctx_b+bv)+bo ---
  small_nn_kernel<<<(HIDD * OD + 255) / 256, 256, 0, stream>>>(wv, ctx_w, T1, HIDD, HIDD, OD);
  small_nn_kernel<<<(HIDD * OD + 255) / 256, 256, 0, stream>>>(wo, T1, W3, HIDD, HIDD, OD);
  small_lin_kernel<<<(HIDD + 255) / 256, 256, 0, stream>>>(ctx_b, wv, bv, t1b, 1, HIDD, HIDD);
  small_lin_kernel<<<(HIDD + 255) / 256, 256, 0, stream>>>(t1b, wo, bo, bp, 1, HIDD, HIDD);

  // --- bf16 casts (T1 dead now; Xh/wlh/wrh live in R3 until ctx is written) ---
  tobf16_kernel<<<(HIDD * OD / 4 + 255) / 256, 256, 0, stream>>>(W3, w3h, HIDD * OD / 4);
  tobf16_kernel<<<(OD * HIDD / 4 + 255) / 256, 256, 0, stream>>>(gi_wl, wlh, OD * HIDD / 4);
  tobf16_kernel<<<(OD * HIDD / 4 + 255) / 256, 256, 0, stream>>>(gi_wr, wrh, OD * HIDD / 4);
  tobf16_kernel<<<(NN * HIDD / 4 + 255) / 256, 256, 0, stream>>>(X, Xh, NN * HIDD / 4);

  // --- kNN: approx bf16 MFMA top-8 -> merge -> exact fp32 refine ---
  rownorm_kernel<<<NN / 4, 256, 0, stream>>>(X, x2);
  dist_topk_mfma<<<dim3(NN / 128, NGRP), 256, 0, stream>>>(Xh, x2, pcd, pci);
  cand_merge_kernel<<<NN / 256, 256, 0, stream>>>(pcd, pci, cand);
  refine_kernel<<<NN / 4, 256, 0, stream>>>(X, x2, cand, knn);

  // --- instance GATv2 (bf16 MFMA projections; pcd/pci dead) ---
  gemm_nt_mfma<<<dim3(NN / 128, OD / 128), 256, 0, stream>>>(Xh, wlh, gi_bl, xl, OD, HIDD);
  gemm_nt_mfma<<<dim3(NN / 128, OD / 128), 256, 0, stream>>>(Xh, wrh, gi_br, xr, OD, HIDD);
  inst_gat_kernel<<<NN, 256, 0, stream>>>(xl, xr, knn, gi_att, gi_bias, cmean, ctx);

  // --- attention chain: attn = ctx @ W3^T + bp (ctx -> bf16 first) ---
  tobf16_kernel<<<(NN * OD / 4 + 255) / 256, 256, 0, stream>>>(ctx, ctxh, NN * OD / 4);
  gemm_nt_mfma<<<dim3(NN / 128, HIDD / 128), 256, 0, stream>>>(ctxh, w3h, bp, attnb, HIDD, OD);

  // --- LN -> LN -> GELU -> classifier ---
  epilogue_kernel<<<NN, 256, 0, stream>>>(X, attnb, ln1_g, ln1_b, ln2_g, ln2_b, gw_w, gw_b, temp, out);
}

// Round 5
// 1805.270 us; speedup vs baseline: 2.1820x; 1.1254x over previous
//
#include <hip/hip_runtime.h>
#include <hip/hip_bf16.h>
#include <hip/hip_fp16.h>
#include <math.h>

#define NN 8192
#define HIDD 768
#define NCLS 18
#define OD 512          // HEADS*GD = 2*256
#define ETOT 342        // 324 class edges + 18 self loops
#define NGRP 16         // column groups for dist kernel
#define NEG 0.2f
#define LN_EPS 1e-5f

typedef __attribute__((ext_vector_type(8))) short bf16x8;
typedef __attribute__((ext_vector_type(4))) float f32x4;

// ---------- sorted top-5 insert (static indices, stays in registers) --------
__device__ __forceinline__ void top5_insert(float s, int idx,
    float& d0, float& d1, float& d2, float& d3, float& d4,
    int& i0, int& i1, int& i2, int& i3, int& i4) {
  if (s >= d4) return;
  if (s < d3) {
    d4 = d3; i4 = i3;
    if (s < d2) {
      d3 = d2; i3 = i2;
      if (s < d1) {
        d2 = d1; i2 = i1;
        if (s < d0) { d1 = d0; i1 = i0; d0 = s; i0 = idx; }
        else        { d1 = s;  i1 = idx; }
      } else { d2 = s; i2 = idx; }
    } else { d3 = s; i3 = idx; }
  } else { d4 = s; i4 = idx; }
}

// ---------- top-8 insert, rank-based so every reg index is static ----------
__device__ __forceinline__ void top8_insert(float s, int idx,
                                            float (&dd)[8], int (&ci)[8]) {
  if (s >= dd[7]) return;
  int rank = 0;
  #pragma unroll
  for (int k = 0; k < 7; ++k) rank += (s >= dd[k]) ? 1 : 0;
  #pragma unroll
  for (int k = 7; k >= 1; --k) {
    if (k > rank) { dd[k] = dd[k-1]; ci[k] = ci[k-1]; }
  }
  #pragma unroll
  for (int k = 0; k < 8; ++k) {
    if (k == rank) { dd[k] = s; ci[k] = idx; }
  }
}

// ---------- async global->LDS 16B (used only in gemm_nt_mfma) ---------------
__device__ __forceinline__ void stage16(const void* g, void* l) {
  __builtin_amdgcn_global_load_lds(
      (const __attribute__((address_space(1))) unsigned int*)g,
      (__attribute__((address_space(3))) unsigned int*)l, 16, 0, 0);
}

// ---------- fp32 -> bf16 (rte) ----------------------------------------------
__global__ __launch_bounds__(256) void tobf16_kernel(const float* __restrict__ src,
    ushort* __restrict__ dst, int n4) {
  int i = blockIdx.x * 256 + threadIdx.x;
  if (i >= n4) return;
  float4 v = ((const float4*)src)[i];
  float vv[4] = {v.x, v.y, v.z, v.w};
  ushort h[4];
  #pragma unroll
  for (int j = 0; j < 4; ++j) {
    __hip_bfloat16 b = __float2bfloat16(vv[j]);
    h[j] = *(ushort*)&b;
  }
  ((ushort4*)dst)[i] = make_ushort4(h[0], h[1], h[2], h[3]);
}

// ---------- stack two 512-length biases into one 1024 buffer -----------------
__global__ __launch_bounds__(256) void stack_bias_kernel(const float* __restrict__ b0,
    const float* __restrict__ b1, float* __restrict__ bb) {
  int i = blockIdx.x * 256 + threadIdx.x;
  if (i < OD) bb[i] = b0[i];
  else if (i < 2 * OD) bb[i] = b1[i - OD];
}

// ---------- row squared norms ------------------------------------------------
__global__ __launch_bounds__(256) void rownorm_kernel(const float* __restrict__ X,
                                                      float* __restrict__ x2) {
  int row = blockIdx.x * 4 + (threadIdx.x >> 6);
  int lane = threadIdx.x & 63;
  const float* xr = X + (size_t)row * HIDD;
  float s = 0.f;
  for (int k = lane; k < HIDD; k += 64) { float v = xr[k]; s += v * v; }
  #pragma unroll
  for (int off = 32; off; off >>= 1) s += __shfl_down(s, off);
  if (lane == 0) x2[row] = s;
}

// ---------- small Y = X @ W^T + b (thread per output) ------------------------
__global__ void small_lin_kernel(const float* __restrict__ X, const float* __restrict__ W,
                                 const float* __restrict__ b, float* __restrict__ Y,
                                 int n, int K, int O) {
  int idx = blockIdx.x * 256 + threadIdx.x;
  if (idx >= n * O) return;
  int row = idx / O, o = idx - row * O;
  const float* xr = X + (size_t)row * K;
  const float* wr = W + (size_t)o * K;
  float acc = 0.f;
  for (int k = 0; k < K; ++k) acc += xr[k] * wr[k];
  Y[idx] = acc + b[o];
}

// ---------- small C = A @ B (thread per output) ------------------------------
__global__ void small_nn_kernel(const float* __restrict__ A, const float* __restrict__ B,
                                float* __restrict__ C, int M, int K, int Nc) {
  int idx = blockIdx.x * 256 + threadIdx.x;
  if (idx >= M * Nc) return;
  int i = idx / Nc, j = idx - i * Nc;
  float acc = 0.f;
  for (int k = 0; k < K; ++k) acc += A[(size_t)i * K + k] * B[(size_t)k * Nc + j];
  C[idx] = acc;
}

// ---------- class-graph GATv2 -> mean over nodes (single block) --------------
__global__ __launch_bounds__(256) void class_gat_kernel(const int* __restrict__ ei,
    const float* __restrict__ xlc, const float* __restrict__ xrc,
    const float* __restrict__ att, const float* __restrict__ bias,
    float* __restrict__ cmean) {
  __shared__ float sc[ETOT * 2];
  __shared__ int es[ETOT], ed[ETOT];
  __shared__ float mx[NCLS][2], sm[NCLS][2];
  int tid = threadIdx.x;
  for (int e = tid; e < ETOT; e += 256) {
    if (e < 324) { es[e] = ei[e]; ed[e] = ei[324 + e]; }
    else         { es[e] = e - 324; ed[e] = e - 324; }
  }
  __syncthreads();
  int lane = tid & 63, w = tid >> 6;
  for (int t = w; t < ETOT * 2; t += 4) {
    int e = t >> 1, h = t & 1;
    const float* xlr = xlc + (size_t)es[e] * OD + h * 256;
    const float* xrr = xrc + (size_t)ed[e] * OD + h * 256;
    const float* ar  = att + h * 256;
    float s = 0.f;
    for (int d = lane; d < 256; d += 64) {
      float v = xlr[d] + xrr[d];
      v = v > 0.f ? v : NEG * v;
      s += v * ar[d];
    }
    #pragma unroll
    for (int off = 32; off; off >>= 1) s += __shfl_down(s, off);
    if (lane == 0) sc[t] = s;
  }
  __syncthreads();
  if (tid < NCLS * 2) {
    int d = tid >> 1, h = tid & 1;
    float m = -3e38f;
    for (int e = 0; e < ETOT; ++e) if (ed[e] == d) m = fmaxf(m, sc[e * 2 + h]);
    float ssum = 0.f;
    for (int e = 0; e < ETOT; ++e) if (ed[e] == d) ssum += expf(sc[e * 2 + h] - m);
    mx[d][h] = m; sm[d][h] = 1.f / ssum;
  }
  __syncthreads();
  for (int t = tid; t < ETOT * 2; t += 256) {
    int e = t >> 1, h = t & 1;
    sc[t] = expf(sc[t] - mx[ed[e]][h]) * sm[ed[e]][h];
  }
  __syncthreads();
  for (int c = tid; c < OD; c += 256) {
    int h = c >> 8;
    float acc = 0.f;
    for (int e = 0; e < ETOT; ++e) acc += sc[e * 2 + h] * xlc[(size_t)es[e] * OD + c];
    cmean[c] = acc * (1.f / 18.f) + bias[c];
  }
}

// ---------- stage 1: bf16 MFMA distances + per-row approx top-8 --------------
// 128x128 tile / block (4 waves of 64x64), BK=64, cols split into NGRP groups.
// 33 KB LDS (score tile unions the staging buffers; plain ds ops + barriers,
// no DMA in this kernel) -> 4 blocks/CU. Scan: 256 threads, half-row each.
__global__ __launch_bounds__(256) void dist_topk_mfma(
    const ushort* __restrict__ Xh, const float* __restrict__ x2,
    float* __restrict__ pcd, int* __restrict__ pci) {
  __shared__ __align__(16) char lds[32768];   // sA|sB staging ∪ Dh scores ∪ merge
  __shared__ float c2s[128];
  char* const sA = lds;
  char* const sB = lds + 16384;
  __half* const Dh = (__half*)lds;            // 128x128 f16 = 32 KB
  float* const cs = (float*)lds;              // merge scores [256][8] = 8 KB
  int*   const cx = (int*)(lds + 8192);       // merge indices [256][8] = 8 KB

  const int tid = threadIdx.x;
  const int lane = tid & 63, wid = tid >> 6;
  const int fr = lane & 15, fq = lane >> 4;
  const int r0 = blockIdx.x * 128;
  const int grp = blockIdx.y;
  const int wr = (wid >> 1) * 64, wc = (wid & 1) * 64;
  const int srow = tid & 127, shalf = tid >> 7;   // scan: row + half ownership

  float dd[8]; int ci[8];
  #pragma unroll
  for (int k = 0; k < 8; ++k) { dd[k] = 3e38f; ci[k] = 0; }

  for (int jt = 0; jt < (NN / NGRP) / 128; ++jt) {
    const int c0 = grp * (NN / NGRP) + jt * 128;
    __syncthreads();                         // prev tile's scan fully done
    if (tid < 128) c2s[tid] = x2[c0 + tid];
    f32x4 acc[4][4] = {};
    for (int kt = 0; kt < HIDD; kt += 64) {
      __syncthreads();                       // frag reads / scan of prev phase done
      // reg-staged: load bf16x8 from global, ds_write to swizzled slot.
      // write swizzle (chunk ^ row&7) matches the read swizzle below.
      #pragma unroll
      for (int q = 0; q < 4; ++q) {
        const int chunkid = q * 256 + tid;
        const int row = chunkid >> 3, cc = chunkid & 7;
        const bf16x8 va = *(const bf16x8*)(Xh + (size_t)(r0 + row) * HIDD + kt + cc * 8);
        const bf16x8 vb = *(const bf16x8*)(Xh + (size_t)(c0 + row) * HIDD + kt + cc * 8);
        const int wi = row * 128 + ((cc ^ (row & 7)) << 4);
        *(bf16x8*)(sA + wi) = va;
        *(bf16x8*)(sB + wi) = vb;
      }
      __syncthreads();                       // staged data visible
      #pragma unroll
      for (int kk = 0; kk < 2; ++kk) {
        bf16x8 ah[4], bh[4];
        #pragma unroll
        for (int m = 0; m < 4; ++m) {
          const int ar = wr + m * 16 + fr;
          const int off = ar * 128 + (((kk * 4 + fq) ^ (ar & 7)) << 4);
          ah[m] = *(const bf16x8*)(sA + off);
        }
        #pragma unroll
        for (int n = 0; n < 4; ++n) {
          const int br = wc + n * 16 + fr;
          const int off = br * 128 + (((kk * 4 + fq) ^ (br & 7)) << 4);
          bh[n] = *(const bf16x8*)(sB + off);
        }
        #pragma unroll
        for (int m = 0; m < 4; ++m)
          #pragma unroll
          for (int n = 0; n < 4; ++n)
            acc[m][n] = __builtin_amdgcn_mfma_f32_16x16x32_bf16(ah[m], bh[n], acc[m][n], 0, 0, 0);
      }
    }
    __syncthreads();                         // all frag reads done; overlay Dh
    // store -2*dot as f16, col slot rotated by row (conflict-light scan)
    #pragma unroll
    for (int n = 0; n < 4; ++n) {
      const int col = wc + n * 16 + fr;
      #pragma unroll
      for (int m = 0; m < 4; ++m) {
        #pragma unroll
        for (int j = 0; j < 4; ++j) {
          const int row = wr + m * 16 + fq * 4 + j;
          Dh[row * 128 + ((col + row) & 127)] = __float2half(-2.0f * acc[m][n][j]);
        }
      }
    }
    __syncthreads();
    // scan: all 256 threads, one half-row (64 cols) each, running top-8
    {
      const int r = srow;
      for (int c = 0; c < 64; ++c) {
        const int col = shalf * 64 + c;
        const float s = c2s[col] + __half2float(Dh[r * 128 + ((col + r) & 127)]);
        top8_insert(s, c0 + col, dd, ci);
      }
    }
  }
  // merge the two half-lists per row (overlay staging region; barriers guard)
  __syncthreads();
  #pragma unroll
  for (int k = 0; k < 8; ++k) { cs[tid * 8 + k] = dd[k]; cx[tid * 8 + k] = ci[k]; }
  __syncthreads();
  if (tid < 128) {
    float md[8]; int mi[8];
    #pragma unroll
    for (int k = 0; k < 8; ++k) { md[k] = cs[tid * 8 + k]; mi[k] = cx[tid * 8 + k]; }
    const int src = tid + 128;
    #pragma unroll
    for (int k = 0; k < 8; ++k) top8_insert(cs[src * 8 + k], cx[src * 8 + k], md, mi);
    const size_t base = ((size_t)(r0 + tid) * NGRP + grp) * 8;
    #pragma unroll
    for (int k = 0; k < 8; ++k) { pcd[base + k] = md[k]; pci[base + k] = mi[k]; }
  }
}

// ---------- merge NGRP approx top-8 lists -> per-row top-8 candidates --------
__global__ __launch_bounds__(256) void cand_merge_kernel(const float* __restrict__ pcd,
    const int* __restrict__ pci, int* __restrict__ cand) {
  const int row = blockIdx.x * 256 + threadIdx.x;
  if (row >= NN) return;
  float dd[8]; int ci[8];
  #pragma unroll
  for (int k = 0; k < 8; ++k) { dd[k] = 3e38f; ci[k] = 0; }
  for (int g = 0; g < NGRP; ++g) {
    const size_t base = ((size_t)row * NGRP + g) * 8;
    #pragma unroll
    for (int k = 0; k < 8; ++k) top8_insert(pcd[base + k], pci[base + k], dd, ci);
  }
  #pragma unroll
  for (int k = 0; k < 8; ++k) cand[row * 8 + k] = ci[k];
}

// ---------- stage 2: exact fp32 refine of 8 candidates -> exact top-5 --------
__global__ __launch_bounds__(256) void refine_kernel(const float* __restrict__ X,
    const float* __restrict__ x2, const int* __restrict__ cand, int* __restrict__ knn) {
  const int row = blockIdx.x * 4 + (threadIdx.x >> 6);
  const int lane = threadIdx.x & 63;
  int c[8];
  #pragma unroll
  for (int k = 0; k < 8; ++k) c[k] = cand[row * 8 + k];
  const float* xi = X + (size_t)row * HIDD;
  float acc[8] = {};
  for (int d = lane; d < HIDD; d += 64) {
    const float a = xi[d];
    #pragma unroll
    for (int k = 0; k < 8; ++k) acc[k] += a * X[(size_t)c[k] * HIDD + d];
  }
  #pragma unroll
  for (int k = 0; k < 8; ++k) {
    #pragma unroll
    for (int off = 32; off; off >>= 1) acc[k] += __shfl_down(acc[k], off);
  }
  if (lane == 0) {
    float d0 = 3e38f, d1 = 3e38f, d2 = 3e38f, d3 = 3e38f, d4 = 3e38f;
    int i0 = 0, i1 = 0, i2 = 0, i3 = 0, i4 = 0;
    #pragma unroll
    for (int k = 0; k < 8; ++k) {
      const float s = x2[c[k]] - 2.0f * acc[k];
      top5_insert(s, c[k], d0, d1, d2, d3, d4, i0, i1, i2, i3, i4);
    }
    knn[row * 5 + 0] = i0; knn[row * 5 + 1] = i1; knn[row * 5 + 2] = i2;
    knn[row * 5 + 3] = i3; knn[row * 5 + 4] = i4;
  }
}

// ---------- bf16 MFMA GEMM: C[8192,Nc] = A @ B^T + bias ----------------------
__global__ __launch_bounds__(256) void gemm_nt_mfma(const ushort* __restrict__ A,
    const ushort* __restrict__ B, const float* __restrict__ bias,
    float* __restrict__ C, int Nc, int K) {
  __shared__ char lds[32768];
  char* const pA = lds;
  char* const pB = lds + 16384;
  const int tid = threadIdx.x;
  const int lane = tid & 63, wid = tid >> 6;
  const int fr = lane & 15, fq = lane >> 4;
  const int r0 = blockIdx.x * 128;
  const int c0 = blockIdx.y * 128;
  const int wr = (wid >> 1) * 64, wc = (wid & 1) * 64;
  f32x4 acc[4][4] = {};
  for (int kt = 0; kt < K; kt += 64) {
    __syncthreads();
    #pragma unroll
    for (int q = 0; q < 4; ++q) {
      const int chunk = wid * 256 + q * 64 + lane;
      const int row = chunk >> 3;
      const int lc = (chunk & 7) ^ (row & 7);
      const int ld = wid * 4096 + q * 1024;
      stage16((const char*)A + ((size_t)(r0 + row) * K + kt) * 2 + (size_t)lc * 16, pA + ld);
      stage16((const char*)B + ((size_t)(c0 + row) * K + kt) * 2 + (size_t)lc * 16, pB + ld);
    }
    __syncthreads();
    #pragma unroll
    for (int kk = 0; kk < 2; ++kk) {
      bf16x8 ah[4], bh[4];
      #pragma unroll
      for (int m = 0; m < 4; ++m) {
        const int ar = wr + m * 16 + fr;
        const int off = ar * 128 + (((kk * 4 + fq) ^ (ar & 7)) << 4);
        ah[m] = *(const bf16x8*)(pA + off);
      }
      #pragma unroll
      for (int n = 0; n < 4; ++n) {
        const int br = wc + n * 16 + fr;
        const int off = br * 128 + (((kk * 4 + fq) ^ (br & 7)) << 4);
        bh[n] = *(const bf16x8*)(pB + off);
      }
      #pragma unroll
      for (int m = 0; m < 4; ++m)
        #pragma unroll
        for (int n = 0; n < 4; ++n)
          acc[m][n] = __builtin_amdgcn_mfma_f32_16x16x32_bf16(ah[m], bh[n], acc[m][n], 0, 0, 0);
    }
  }
  #pragma unroll
  for (int n = 0; n < 4; ++n) {
    const int cc = c0 + wc + n * 16 + fr;
    const float bs = bias[cc];
    #pragma unroll
    for (int m = 0; m < 4; ++m) {
      #pragma unroll
      for (int j = 0; j < 4; ++j) {
        const int rr = r0 + wr + m * 16 + fq * 4 + j;
        C[(size_t)rr * Nc + cc] = acc[m][n][j] + bs;
      }
    }
  }
}

// ---------- instance GATv2 aggregation; xl/xr packed as xlr[N][1024] ---------
__global__ __launch_bounds__(256) void inst_gat_kernel(const float* __restrict__ xlr,
    const int* __restrict__ knn, const float* __restrict__ att,
    const float* __restrict__ bias, const float* __restrict__ cmean,
    float* __restrict__ ctx) {
  __shared__ float sc[12];
  __shared__ float alpha[12];
  __shared__ int nbr[6];
  const int i = blockIdx.x;
  const int tid = threadIdx.x;
  if (tid < 5) nbr[tid] = knn[i * 5 + tid];
  else if (tid == 5) nbr[5] = i;   // explicit self loop (in addition to knn self)
  __syncthreads();
  int lane = tid & 63, w = tid >> 6;
  for (int t = w; t < 12; t += 4) {
    int e = t >> 1, h = t & 1;
    const float* xlrow = xlr + (size_t)nbr[e] * 1024 + h * 256;
    const float* xrrow = xlr + (size_t)i * 1024 + 512 + h * 256;
    const float* ar  = att + h * 256;
    float s = 0.f;
    #pragma unroll
    for (int q = 0; q < 4; ++q) {
      int d = lane + q * 64;
      float v = xlrow[d] + xrrow[d];
      v = v > 0.f ? v : NEG * v;
      s += v * ar[d];
    }
    #pragma unroll
    for (int off = 32; off; off >>= 1) s += __shfl_down(s, off);
    if (lane == 0) sc[t] = s;
  }
  __syncthreads();
  if (tid < 2) {
    int h = tid;
    float m = -3e38f;
    #pragma unroll
    for (int e = 0; e < 6; ++e) m = fmaxf(m, sc[e * 2 + h]);
    float ssum = 0.f;
    #pragma unroll
    for (int e = 0; e < 6; ++e) { float ex = expf(sc[e * 2 + h] - m); alpha[e * 2 + h] = ex; ssum += ex; }
    float inv = 1.f / ssum;
    #pragma unroll
    for (int e = 0; e < 6; ++e) alpha[e * 2 + h] *= inv;
  }
  __syncthreads();
  for (int c = tid; c < OD; c += 256) {
    int h = c >> 8;
    float acc = 0.f;
    #pragma unroll
    for (int e = 0; e < 6; ++e) acc += alpha[e * 2 + h] * xlr[(size_t)nbr[e] * 1024 + c];
    ctx[(size_t)i * OD + c] = acc + bias[c] + cmean[c];
  }
}

// ---------- fused epilogue: LN1 -> LN2 -> GELU -> 18-way classifier ----------
__global__ __launch_bounds__(256) void epilogue_kernel(const float* __restrict__ inst,
    const float* __restrict__ attn, const float* __restrict__ g1, const float* __restrict__ b1,
    const float* __restrict__ g2, const float* __restrict__ b2, const float* __restrict__ gw,
    const float* __restrict__ gb, const float* __restrict__ temp, float* __restrict__ out) {
  __shared__ float buf[HIDD];
  __shared__ float red[4];
  const int i = blockIdx.x;
  const int tid = threadIdx.x;
  const int lane = tid & 63, w = tid >> 6;
  size_t base = (size_t)i * HIDD;
  float v0 = inst[base + tid]       + attn[base + tid];
  float v1 = inst[base + tid + 256] + attn[base + tid + 256];
  float v2 = inst[base + tid + 512] + attn[base + tid + 512];

  float s = v0 + v1 + v2;
  #pragma unroll
  for (int off = 32; off; off >>= 1) s += __shfl_down(s, off);
  if (lane == 0) red[w] = s;
  __syncthreads();
  float mean = (red[0] + red[1] + red[2] + red[3]) * (1.f / HIDD);
  __syncthreads();
  float e0 = v0 - mean, e1 = v1 - mean, e2 = v2 - mean;
  s = e0 * e0 + e1 * e1 + e2 * e2;
  #pragma unroll
  for (int off = 32; off; off >>= 1) s += __shfl_down(s, off);
  if (lane == 0) red[w] = s;
  __syncthreads();
  float rstd = rsqrtf((red[0] + red[1] + red[2] + red[3]) * (1.f / HIDD) + LN_EPS);
  __syncthreads();
  float y0 = e0 * rstd * g1[tid]       + b1[tid];
  float y1 = e1 * rstd * g1[tid + 256] + b1[tid + 256];
  float y2 = e2 * rstd * g1[tid + 512] + b1[tid + 512];

  s = y0 + y1 + y2;
  #pragma unroll
  for (int off = 32; off; off >>= 1) s += __shfl_down(s, off);
  if (lane == 0) red[w] = s;
  __syncthreads();
  float mean2 = (red[0] + red[1] + red[2] + red[3]) * (1.f / HIDD);
  __syncthreads();
  float f0 = y0 - mean2, f1 = y1 - mean2, f2 = y2 - mean2;
  s = f0 * f0 + f1 * f1 + f2 * f2;
  #pragma unroll
  for (int off = 32; off; off >>= 1) s += __shfl_down(s, off);
  if (lane == 0) red[w] = s;
  __syncthreads();
  float rstd2 = rsqrtf((red[0] + red[1] + red[2] + red[3]) * (1.f / HIDD) + LN_EPS);
  float z0 = f0 * rstd2 * g2[tid]       + b2[tid];
  float z1 = f1 * rstd2 * g2[tid + 256] + b2[tid + 256];
  float z2 = f2 * rstd2 * g2[tid + 512] + b2[tid + 512];
  buf[tid]       = 0.5f * z0 * (1.f + erff(z0 * 0.70710678118654752f));
  buf[tid + 256] = 0.5f * z1 * (1.f + erff(z1 * 0.70710678118654752f));
  buf[tid + 512] = 0.5f * z2 * (1.f + erff(z2 * 0.70710678118654752f));
  __syncthreads();

  float invT = 1.f / temp[0];
  for (int c = w; c < NCLS; c += 4) {
    const float* wr = gw + (size_t)c * HIDD;
    float acc = 0.f;
    for (int d = lane; d < HIDD; d += 64) acc += buf[d] * wr[d];
    #pragma unroll
    for (int off = 32; off; off >>= 1) acc += __shfl_down(acc, off);
    if (lane == 0) out[(size_t)i * NCLS + c] = (acc + gb[c]) * invT;
  }
}

// ---------------------------------------------------------------------------
extern "C" void kernel_launch(void* const* d_in, const int* in_sizes, int n_in,
                              void* d_out, int out_size, void* d_ws, size_t ws_size,
                              hipStream_t stream) {
  (void)in_sizes; (void)n_in; (void)out_size; (void)ws_size;
  const float* X       = (const float*)d_in[0];
  const int*   cei     = (const int*)  d_in[1];
  const float* cemb    = (const float*)d_in[2];
  const float* gc_wl   = (const float*)d_in[3];
  const float* gc_bl   = (const float*)d_in[4];
  const float* gc_wr   = (const float*)d_in[5];
  const float* gc_br   = (const float*)d_in[6];
  const float* gc_att  = (const float*)d_in[7];
  const float* gc_bias = (const float*)d_in[8];
  const float* gi_wl   = (const float*)d_in[9];
  const float* gi_bl   = (const float*)d_in[10];
  const float* gi_wr   = (const float*)d_in[11];
  const float* gi_br   = (const float*)d_in[12];
  const float* gi_att  = (const float*)d_in[13];
  const float* gi_bias = (const float*)d_in[14];
  // d_in[15]=q_w, d_in[16]=q_b: cancel out of the forward value (seq_len 1)
  const float* ctx_w   = (const float*)d_in[17];
  const float* ctx_b   = (const float*)d_in[18];
  const float* wv      = (const float*)d_in[19];
  const float* bv      = (const float*)d_in[20];
  const float* wo      = (const float*)d_in[21];
  const float* bo      = (const float*)d_in[22];
  const float* ln1_g   = (const float*)d_in[23];
  const float* ln1_b   = (const float*)d_in[24];
  const float* ln2_g   = (const float*)d_in[25];
  const float* ln2_b   = (const float*)d_in[26];
  const float* gw_w    = (const float*)d_in[27];
  const float* gw_b    = (const float*)d_in[28];
  const float* temp    = (const float*)d_in[29];
  float* out = (float*)d_out;

  // ---- workspace layout (f32 units). R1,R2,R3 are 4.19M f32 each. ----
  // Liveness (write-before-read on every call):
  //   R1: pcd/pci (dist->cand_merge) -> xlr head (gemm->inst_gat) -> ctxh
  //   R2: T1 (small_nn->small_nn) -> xlr tail -> attnb head (gemm->epilogue)
  //   R3: Xh+wlrh (tobf16->dist/gemms) -> ctx (inst_gat->tobf16) -> attnb tail
  //   R4: x2, W3, w3h, t1b, bp, bb, cand, knn, xlc, xrc, cmean (no overlays)
  float* ws  = (float*)d_ws;
  float* R1  = ws;
  float* R2  = R1 + (size_t)NN * OD;
  float* R3  = R2 + (size_t)NN * OD;
  float* R4  = R3 + (size_t)NN * OD;

  // R4 sublayout
  float* x2    = R4;                                   // 8192
  float* W3    = x2 + NN;                              // 768*512 f32
  ushort* w3h  = (ushort*)(W3 + (size_t)HIDD * OD);    // 768*512 bf16
  float* t1b   = (float*)(w3h + (size_t)HIDD * OD);    // 768
  float* bp    = t1b + HIDD;                           // 768
  float* bb    = bp + HIDD;                            // 1024 stacked bias
  int*   cand  = (int*)(bb + 2 * OD);                  // 8192*8
  int*   knn   = cand + NN * 8;                        // 8192*5
  float* xlc   = (float*)(knn + NN * 5);               // 18*512
  float* xrc   = xlc + NCLS * OD;                      // 18*512
  float* cmean = xrc + NCLS * OD;                      // 512

  // aliases
  float* pcd   = R1;                                   // 8192*16*8 f32
  int*   pci   = (int*)(pcd + (size_t)NN * NGRP * 8);  // 8192*16*8 int
  float* xlr   = R1;                                   // 8192*1024 f32 (R1+R2)
  ushort* ctxh = (ushort*)R1;                          // 8192*512 bf16 (xlr dead)
  float* T1    = R2;                                   // 768*512 f32 (dead before xlr)
  float* ctx   = R3;
  ushort* Xh   = (ushort*)R3;                          // 8192*768 bf16 (dead before ctx)
  ushort* wlrh = (ushort*)(R3 + (size_t)NN * HIDD / 2);// 1024*768 bf16 stacked wl|wr
  float* attnb = R2;   // 8192*768 f32, spans R2 + head of R3 (both dead)

  // --- class path -> cmean[512] (independent) ---
  small_lin_kernel<<<(NCLS * OD + 255) / 256, 256, 0, stream>>>(cemb, gc_wl, gc_bl, xlc, NCLS, HIDD, OD);
  small_lin_kernel<<<(NCLS * OD + 255) / 256, 256, 0, stream>>>(cemb, gc_wr, gc_br, xrc, NCLS, HIDD, OD);
  class_gat_kernel<<<1, 256, 0, stream>>>(cei, xlc, xrc, gc_att, gc_bias, cmean);

  // --- fold attention weights: W3 = wo @ wv @ ctx_w, bp = wo@(wv@ctx_b+bv)+bo ---
  small_nn_kernel<<<(HIDD * OD + 255) / 256, 256, 0, stream>>>(wv, ctx_w, T1, HIDD, HIDD, OD);
  small_nn_kernel<<<(HIDD * OD + 255) / 256, 256, 0, stream>>>(wo, T1, W3, HIDD, HIDD, OD);
  small_lin_kernel<<<(HIDD + 255) / 256, 256, 0, stream>>>(ctx_b, wv, bv, t1b, 1, HIDD, HIDD);
  small_lin_kernel<<<(HIDD + 255) / 256, 256, 0, stream>>>(t1b, wo, bo, bp, 1, HIDD, HIDD);

  // --- bf16 casts + bias stack (T1 dead now) ---
  tobf16_kernel<<<(HIDD * OD / 4 + 255) / 256, 256, 0, stream>>>(W3, w3h, HIDD * OD / 4);
  tobf16_kernel<<<(OD * HIDD / 4 + 255) / 256, 256, 0, stream>>>(gi_wl, wlrh, OD * HIDD / 4);
  tobf16_kernel<<<(OD * HIDD / 4 + 255) / 256, 256, 0, stream>>>(gi_wr, wlrh + (size_t)OD * HIDD, OD * HIDD / 4);
  tobf16_kernel<<<(NN * HIDD / 4 + 255) / 256, 256, 0, stream>>>(X, Xh, NN * HIDD / 4);
  stack_bias_kernel<<<4, 256, 0, stream>>>(gi_bl, gi_br, bb);

  // --- kNN: approx bf16 MFMA top-8 -> merge -> exact fp32 refine ---
  rownorm_kernel<<<NN / 4, 256, 0, stream>>>(X, x2);
  dist_topk_mfma<<<dim3(NN / 128, NGRP), 256, 0, stream>>>(Xh, x2, pcd, pci);
  cand_merge_kernel<<<NN / 256, 256, 0, stream>>>(pcd, pci, cand);
  refine_kernel<<<NN / 4, 256, 0, stream>>>(X, x2, cand, knn);

  // --- instance GATv2: fused xl|xr projection (pcd/pci dead) ---
  gemm_nt_mfma<<<dim3(NN / 128, (2 * OD) / 128), 256, 0, stream>>>(Xh, wlrh, bb, xlr, 2 * OD, HIDD);
  inst_gat_kernel<<<NN, 256, 0, stream>>>(xlr, knn, gi_att, gi_bias, cmean, ctx);

  // --- attention chain: attn = ctx @ W3^T + bp (ctx -> bf16 first) ---
  tobf16_kernel<<<(NN * OD / 4 + 255) / 256, 256, 0, stream>>>(ctx, ctxh, NN * OD / 4);
  gemm_nt_mfma<<<dim3(NN / 128, HIDD / 128), 256, 0, stream>>>(ctxh, w3h, bp, attnb, HIDD, OD);

  // --- LN -> LN -> GELU -> classifier ---
  epilogue_kernel<<<NN, 256, 0, stream>>>(X, attnb, ln1_g, ln1_b, ln2_g, ln2_b, gw_w, gw_b, temp, out);
}

// Round 6
// 1486.022 us; speedup vs baseline: 2.6507x; 1.2148x over previous
//
#include <hip/hip_runtime.h>
#include <hip/hip_bf16.h>
#include <hip/hip_fp16.h>
#include <math.h>

#define NN 8192
#define HIDD 768
#define NCLS 18
#define OD 512          // HEADS*GD = 2*256
#define ETOT 342        // 324 class edges + 18 self loops
#define NGRP 16         // column groups for dist kernel
#define NEG 0.2f
#define LN_EPS 1e-5f

typedef __attribute__((ext_vector_type(8))) short bf16x8;
typedef __attribute__((ext_vector_type(4))) float f32x4;

// ---------- sorted top-5 insert (static indices, stays in registers) --------
__device__ __forceinline__ void top5_insert(float s, int idx,
    float& d0, float& d1, float& d2, float& d3, float& d4,
    int& i0, int& i1, int& i2, int& i3, int& i4) {
  if (s >= d4) return;
  if (s < d3) {
    d4 = d3; i4 = i3;
    if (s < d2) {
      d3 = d2; i3 = i2;
      if (s < d1) {
        d2 = d1; i2 = i1;
        if (s < d0) { d1 = d0; i1 = i0; d0 = s; i0 = idx; }
        else        { d1 = s;  i1 = idx; }
      } else { d2 = s; i2 = idx; }
    } else { d3 = s; i3 = idx; }
  } else { d4 = s; i4 = idx; }
}

// ---------- top-8 insert on packed u32 keys (rank-based, static indices) ----
__device__ __forceinline__ void top8k_insert(unsigned key, unsigned (&kk)[8]) {
  if (key >= kk[7]) return;
  int rank = 0;
  #pragma unroll
  for (int k = 0; k < 7; ++k) rank += (key >= kk[k]) ? 1 : 0;
  #pragma unroll
  for (int k = 7; k >= 1; --k) if (k > rank) kk[k] = kk[k-1];
  #pragma unroll
  for (int k = 0; k < 8; ++k) if (k == rank) kk[k] = key;
}

// ---------- async global->LDS 16B (used only in gemm_nt_mfma) ---------------
__device__ __forceinline__ void stage16(const void* g, void* l) {
  __builtin_amdgcn_global_load_lds(
      (const __attribute__((address_space(1))) unsigned int*)g,
      (__attribute__((address_space(3))) unsigned int*)l, 16, 0, 0);
}

// ---------- fp32 -> bf16 (rte) ----------------------------------------------
__global__ __launch_bounds__(256) void tobf16_kernel(const float* __restrict__ src,
    ushort* __restrict__ dst, int n4) {
  int i = blockIdx.x * 256 + threadIdx.x;
  if (i >= n4) return;
  float4 v = ((const float4*)src)[i];
  float vv[4] = {v.x, v.y, v.z, v.w};
  ushort h[4];
  #pragma unroll
  for (int j = 0; j < 4; ++j) {
    __hip_bfloat16 b = __float2bfloat16(vv[j]);
    h[j] = *(ushort*)&b;
  }
  ((ushort4*)dst)[i] = make_ushort4(h[0], h[1], h[2], h[3]);
}

// ---------- fused: X -> Xh (bf16) + row squared norms ------------------------
__global__ __launch_bounds__(256) void rowcast_kernel(const float* __restrict__ X,
    ushort* __restrict__ Xh, float* __restrict__ x2) {
  const int row = blockIdx.x * 4 + (threadIdx.x >> 6);
  const int lane = threadIdx.x & 63;
  const float4* src = (const float4*)(X + (size_t)row * HIDD);
  ushort4* dst = (ushort4*)(Xh + (size_t)row * HIDD);
  float s = 0.f;
  #pragma unroll
  for (int q = 0; q < 3; ++q) {
    float4 v = src[lane + q * 64];
    s += v.x * v.x + v.y * v.y + v.z * v.z + v.w * v.w;
    __hip_bfloat16 bx = __float2bfloat16(v.x), by = __float2bfloat16(v.y);
    __hip_bfloat16 bz = __float2bfloat16(v.z), bw = __float2bfloat16(v.w);
    dst[lane + q * 64] = make_ushort4(*(ushort*)&bx, *(ushort*)&by,
                                      *(ushort*)&bz, *(ushort*)&bw);
  }
  #pragma unroll
  for (int off = 32; off; off >>= 1) s += __shfl_down(s, off);
  if (lane == 0) x2[row] = s;
}

// ---------- stack two 512-length biases into one 1024 buffer -----------------
__global__ __launch_bounds__(256) void stack_bias_kernel(const float* __restrict__ b0,
    const float* __restrict__ b1, float* __restrict__ bb) {
  int i = blockIdx.x * 256 + threadIdx.x;
  if (i < OD) bb[i] = b0[i];
  else if (i < 2 * OD) bb[i] = b1[i - OD];
}

// ---------- small Y = X @ W^T + b (thread per output) ------------------------
__global__ void small_lin_kernel(const float* __restrict__ X, const float* __restrict__ W,
                                 const float* __restrict__ b, float* __restrict__ Y,
                                 int n, int K, int O) {
  int idx = blockIdx.x * 256 + threadIdx.x;
  if (idx >= n * O) return;
  int row = idx / O, o = idx - row * O;
  const float* xr = X + (size_t)row * K;
  const float* wr = W + (size_t)o * K;
  float acc = 0.f;
  for (int k = 0; k < K; ++k) acc += xr[k] * wr[k];
  Y[idx] = acc + b[o];
}

// ---------- small C = A @ B (thread per output) ------------------------------
__global__ void small_nn_kernel(const float* __restrict__ A, const float* __restrict__ B,
                                float* __restrict__ C, int M, int K, int Nc) {
  int idx = blockIdx.x * 256 + threadIdx.x;
  if (idx >= M * Nc) return;
  int i = idx / Nc, j = idx - i * Nc;
  float acc = 0.f;
  for (int k = 0; k < K; ++k) acc += A[(size_t)i * K + k] * B[(size_t)k * Nc + j];
  C[idx] = acc;
}

// ---------- class-graph GATv2 -> mean over nodes (single block) --------------
__global__ __launch_bounds__(256) void class_gat_kernel(const int* __restrict__ ei,
    const float* __restrict__ xlc, const float* __restrict__ xrc,
    const float* __restrict__ att, const float* __restrict__ bias,
    float* __restrict__ cmean) {
  __shared__ float sc[ETOT * 2];
  __shared__ int es[ETOT], ed[ETOT];
  __shared__ float mx[NCLS][2], sm[NCLS][2];
  int tid = threadIdx.x;
  for (int e = tid; e < ETOT; e += 256) {
    if (e < 324) { es[e] = ei[e]; ed[e] = ei[324 + e]; }
    else         { es[e] = e - 324; ed[e] = e - 324; }
  }
  __syncthreads();
  int lane = tid & 63, w = tid >> 6;
  for (int t = w; t < ETOT * 2; t += 4) {
    int e = t >> 1, h = t & 1;
    const float* xlr = xlc + (size_t)es[e] * OD + h * 256;
    const float* xrr = xrc + (size_t)ed[e] * OD + h * 256;
    const float* ar  = att + h * 256;
    float s = 0.f;
    for (int d = lane; d < 256; d += 64) {
      float v = xlr[d] + xrr[d];
      v = v > 0.f ? v : NEG * v;
      s += v * ar[d];
    }
    #pragma unroll
    for (int off = 32; off; off >>= 1) s += __shfl_down(s, off);
    if (lane == 0) sc[t] = s;
  }
  __syncthreads();
  if (tid < NCLS * 2) {
    int d = tid >> 1, h = tid & 1;
    float m = -3e38f;
    for (int e = 0; e < ETOT; ++e) if (ed[e] == d) m = fmaxf(m, sc[e * 2 + h]);
    float ssum = 0.f;
    for (int e = 0; e < ETOT; ++e) if (ed[e] == d) ssum += expf(sc[e * 2 + h] - m);
    mx[d][h] = m; sm[d][h] = 1.f / ssum;
  }
  __syncthreads();
  for (int t = tid; t < ETOT * 2; t += 256) {
    int e = t >> 1, h = t & 1;
    sc[t] = expf(sc[t] - mx[ed[e]][h]) * sm[ed[e]][h];
  }
  __syncthreads();
  for (int c = tid; c < OD; c += 256) {
    int h = c >> 8;
    float acc = 0.f;
    for (int e = 0; e < ETOT; ++e) acc += sc[e * 2 + h] * xlc[(size_t)es[e] * OD + c];
    cmean[c] = acc * (1.f / 18.f) + bias[c];
  }
}

// ---------- stage 1: bf16 MFMA distances + per-row approx top-8 (packed keys)
// 128x128 tile / block (4 waves of 64x64), BK=64, NGRP column groups.
// Forced 4 waves/SIMD (<=128 VGPR) -> 4 blocks/CU at 33 KB LDS.
// Keys: monotone-f16(score-768) << 16 | global col (13 bits).
__global__ __launch_bounds__(256, 4) void dist_topk_mfma(
    const ushort* __restrict__ Xh, const float* __restrict__ x2,
    unsigned* __restrict__ pck) {
  __shared__ __align__(16) char lds[32768];   // sA|sB staging ∪ Dk keys ∪ merge
  __shared__ float c2s[128];
  char* const sA = lds;
  char* const sB = lds + 16384;
  ushort* const Dk = (ushort*)lds;            // 128x128 u16 keys = 32 KB
  unsigned* const ck = (unsigned*)lds;        // merge [256][8] u32 = 8 KB

  const int tid = threadIdx.x;
  const int lane = tid & 63, wid = tid >> 6;
  const int fr = lane & 15, fq = lane >> 4;
  const int r0 = blockIdx.x * 128;
  const int grp = blockIdx.y;
  const int wr = (wid >> 1) * 64, wc = (wid & 1) * 64;
  const int srow = tid & 127, shalf = tid >> 7;

  unsigned keys[8];
  #pragma unroll
  for (int k = 0; k < 8; ++k) keys[k] = 0xFFFFFFFFu;

  for (int jt = 0; jt < (NN / NGRP) / 128; ++jt) {
    const int c0 = grp * (NN / NGRP) + jt * 128;
    __syncthreads();                         // prev tile scan done (c2s/Dk free)
    if (tid < 128) c2s[tid] = x2[c0 + tid];
    f32x4 acc[4][4] = {};
    for (int kt = 0; kt < HIDD; kt += 64) {
      __syncthreads();                       // prior LDS readers done
      // reg-staged: global bf16x8 -> swizzled ds_write (both-sides swizzle)
      #pragma unroll
      for (int q = 0; q < 4; ++q) {
        const int chunkid = q * 256 + tid;
        const int row = chunkid >> 3, cc = chunkid & 7;
        const bf16x8 va = *(const bf16x8*)(Xh + (size_t)(r0 + row) * HIDD + kt + cc * 8);
        const bf16x8 vb = *(const bf16x8*)(Xh + (size_t)(c0 + row) * HIDD + kt + cc * 8);
        const int wi = row * 128 + ((cc ^ (row & 7)) << 4);
        *(bf16x8*)(sA + wi) = va;
        *(bf16x8*)(sB + wi) = vb;
      }
      __syncthreads();                       // staged data visible
      #pragma unroll
      for (int kk = 0; kk < 2; ++kk) {
        bf16x8 bh[4];
        #pragma unroll
        for (int n = 0; n < 4; ++n) {
          const int br = wc + n * 16 + fr;
          bh[n] = *(const bf16x8*)(sB + br * 128 + (((kk * 4 + fq) ^ (br & 7)) << 4));
        }
        #pragma unroll
        for (int m = 0; m < 4; ++m) {
          const int ar = wr + m * 16 + fr;
          const bf16x8 a = *(const bf16x8*)(sA + ar * 128 + (((kk * 4 + fq) ^ (ar & 7)) << 4));
          #pragma unroll
          for (int n = 0; n < 4; ++n)
            acc[m][n] = __builtin_amdgcn_mfma_f32_16x16x32_bf16(a, bh[n], acc[m][n], 0, 0, 0);
        }
      }
    }
    __syncthreads();                         // all frag reads done; overlay Dk
    // write monotone-mapped f16 keys (score - 768 bias keeps f16 quantum small)
    #pragma unroll
    for (int n = 0; n < 4; ++n) {
      const int col = wc + n * 16 + fr;
      const float c2 = c2s[col] - 768.0f;
      #pragma unroll
      for (int m = 0; m < 4; ++m) {
        #pragma unroll
        for (int j = 0; j < 4; ++j) {
          const int row = wr + m * 16 + fq * 4 + j;
          const float s = c2 - 2.0f * acc[m][n][j];
          const ushort u = __half_as_ushort(__float2half(s));
          const ushort k16 = (u & 0x8000) ? (ushort)(~u) : (ushort)(u | 0x8000);
          Dk[row * 128 + ((col + row) & 127)] = k16;
        }
      }
    }
    __syncthreads();
    // scan: 256 threads, one half-row (64 cols) each, running top-8 keys
    {
      const int r = srow;
      for (int c = 0; c < 64; ++c) {
        const int col = shalf * 64 + c;
        const unsigned key =
            ((unsigned)Dk[r * 128 + ((col + r) & 127)] << 16) | (unsigned)(c0 + col);
        top8k_insert(key, keys);
      }
    }
  }
  // merge the two half-lists per row (overlay; barrier-guarded)
  __syncthreads();
  #pragma unroll
  for (int k = 0; k < 8; ++k) ck[tid * 8 + k] = keys[k];
  __syncthreads();
  if (tid < 128) {
    unsigned mk[8];
    #pragma unroll
    for (int k = 0; k < 8; ++k) mk[k] = ck[tid * 8 + k];
    const int src = tid + 128;
    #pragma unroll
    for (int k = 0; k < 8; ++k) top8k_insert(ck[src * 8 + k], mk);
    const size_t base = ((size_t)grp * NN + (r0 + tid)) * 8;   // [g][row][8]
    #pragma unroll
    for (int k = 0; k < 8; ++k) pck[base + k] = mk[k];
  }
}

// ---------- merge NGRP key lists -> per-row top-8 candidate indices ----------
__global__ __launch_bounds__(256) void cand_merge_kernel(const unsigned* __restrict__ pck,
    int* __restrict__ cand) {
  const int row = blockIdx.x * 256 + threadIdx.x;
  if (row >= NN) return;
  unsigned best[8];
  #pragma unroll
  for (int k = 0; k < 8; ++k) best[k] = 0xFFFFFFFFu;
  for (int g = 0; g < NGRP; ++g) {
    const size_t base = ((size_t)g * NN + row) * 8;
    #pragma unroll
    for (int k = 0; k < 8; ++k) top8k_insert(pck[base + k], best);
  }
  #pragma unroll
  for (int k = 0; k < 8; ++k) cand[row * 8 + k] = (int)(best[k] & 0xFFFFu);
}

// ---------- stage 2: exact fp32 refine of 8 candidates -> exact top-5 --------
__global__ __launch_bounds__(256) void refine_kernel(const float* __restrict__ X,
    const float* __restrict__ x2, const int* __restrict__ cand, int* __restrict__ knn) {
  const int row = blockIdx.x * 4 + (threadIdx.x >> 6);
  const int lane = threadIdx.x & 63;
  int c[8];
  #pragma unroll
  for (int k = 0; k < 8; ++k) c[k] = cand[row * 8 + k];
  const float4* xi = (const float4*)(X + (size_t)row * HIDD);
  float acc[8] = {};
  #pragma unroll
  for (int q = 0; q < 3; ++q) {
    const float4 a = xi[lane + q * 64];
    #pragma unroll
    for (int k = 0; k < 8; ++k) {
      const float4 b = ((const float4*)(X + (size_t)c[k] * HIDD))[lane + q * 64];
      acc[k] += a.x * b.x + a.y * b.y + a.z * b.z + a.w * b.w;
    }
  }
  #pragma unroll
  for (int k = 0; k < 8; ++k) {
    #pragma unroll
    for (int off = 32; off; off >>= 1) acc[k] += __shfl_down(acc[k], off);
  }
  if (lane == 0) {
    float d0 = 3e38f, d1 = 3e38f, d2 = 3e38f, d3 = 3e38f, d4 = 3e38f;
    int i0 = 0, i1 = 0, i2 = 0, i3 = 0, i4 = 0;
    #pragma unroll
    for (int k = 0; k < 8; ++k) {
      const float s = x2[c[k]] - 2.0f * acc[k];
      top5_insert(s, c[k], d0, d1, d2, d3, d4, i0, i1, i2, i3, i4);
    }
    knn[row * 5 + 0] = i0; knn[row * 5 + 1] = i1; knn[row * 5 + 2] = i2;
    knn[row * 5 + 3] = i3; knn[row * 5 + 4] = i4;
  }
}

// ---------- bf16 MFMA GEMM: C[8192,Nc] = A @ B^T + bias ----------------------
__global__ __launch_bounds__(256) void gemm_nt_mfma(const ushort* __restrict__ A,
    const ushort* __restrict__ B, const float* __restrict__ bias,
    float* __restrict__ C, int Nc, int K) {
  __shared__ char lds[32768];
  char* const pA = lds;
  char* const pB = lds + 16384;
  const int tid = threadIdx.x;
  const int lane = tid & 63, wid = tid >> 6;
  const int fr = lane & 15, fq = lane >> 4;
  const int r0 = blockIdx.x * 128;
  const int c0 = blockIdx.y * 128;
  const int wr = (wid >> 1) * 64, wc = (wid & 1) * 64;
  f32x4 acc[4][4] = {};
  for (int kt = 0; kt < K; kt += 64) {
    __syncthreads();
    #pragma unroll
    for (int q = 0; q < 4; ++q) {
      const int chunk = wid * 256 + q * 64 + lane;
      const int row = chunk >> 3;
      const int lc = (chunk & 7) ^ (row & 7);
      const int ld = wid * 4096 + q * 1024;
      stage16((const char*)A + ((size_t)(r0 + row) * K + kt) * 2 + (size_t)lc * 16, pA + ld);
      stage16((const char*)B + ((size_t)(c0 + row) * K + kt) * 2 + (size_t)lc * 16, pB + ld);
    }
    __syncthreads();
    #pragma unroll
    for (int kk = 0; kk < 2; ++kk) {
      bf16x8 ah[4], bh[4];
      #pragma unroll
      for (int m = 0; m < 4; ++m) {
        const int ar = wr + m * 16 + fr;
        ah[m] = *(const bf16x8*)(pA + ar * 128 + (((kk * 4 + fq) ^ (ar & 7)) << 4));
      }
      #pragma unroll
      for (int n = 0; n < 4; ++n) {
        const int br = wc + n * 16 + fr;
        bh[n] = *(const bf16x8*)(pB + br * 128 + (((kk * 4 + fq) ^ (br & 7)) << 4));
      }
      #pragma unroll
      for (int m = 0; m < 4; ++m)
        #pragma unroll
        for (int n = 0; n < 4; ++n)
          acc[m][n] = __builtin_amdgcn_mfma_f32_16x16x32_bf16(ah[m], bh[n], acc[m][n], 0, 0, 0);
    }
  }
  #pragma unroll
  for (int n = 0; n < 4; ++n) {
    const int cc = c0 + wc + n * 16 + fr;
    const float bs = bias[cc];
    #pragma unroll
    for (int m = 0; m < 4; ++m) {
      #pragma unroll
      for (int j = 0; j < 4; ++j) {
        const int rr = r0 + wr + m * 16 + fq * 4 + j;
        C[(size_t)rr * Nc + cc] = acc[m][n][j] + bs;
      }
    }
  }
}

// ---------- instance GATv2; xlr packed [N][1024]; rows staged in LDS once ----
__global__ __launch_bounds__(256) void inst_gat_kernel(const float* __restrict__ xlr,
    const int* __restrict__ knn, const float* __restrict__ att,
    const float* __restrict__ bias, const float* __restrict__ cmean,
    float* __restrict__ ctx) {
  __shared__ float rows[7][512];   // 6 neighbor xl rows + own xr row
  __shared__ float sc[12];
  __shared__ float alpha[12];
  __shared__ int nbr[6];
  const int i = blockIdx.x;
  const int tid = threadIdx.x;
  if (tid < 5) nbr[tid] = knn[i * 5 + tid];
  else if (tid == 5) nbr[5] = i;   // explicit self loop
  __syncthreads();
  // stage all needed rows (float4 coalesced)
  for (int t = tid; t < 7 * 128; t += 256) {
    const int rr = t >> 7, e4 = t & 127;
    const float* src = (rr < 6) ? (xlr + (size_t)nbr[rr] * 1024)
                                : (xlr + (size_t)i * 1024 + 512);
    ((float4*)rows[rr])[e4] = ((const float4*)src)[e4];
  }
  __syncthreads();
  const int lane = tid & 63, w = tid >> 6;
  for (int t = w; t < 12; t += 4) {
    const int e = t >> 1, h = t & 1;
    const float* ar = att + h * 256;
    float s = 0.f;
    #pragma unroll
    for (int q = 0; q < 4; ++q) {
      const int d = lane + q * 64;
      float v = rows[e][h * 256 + d] + rows[6][h * 256 + d];
      v = v > 0.f ? v : NEG * v;
      s += v * ar[d];
    }
    #pragma unroll
    for (int off = 32; off; off >>= 1) s += __shfl_down(s, off);
    if (lane == 0) sc[t] = s;
  }
  __syncthreads();
  if (tid < 2) {
    const int h = tid;
    float m = -3e38f;
    #pragma unroll
    for (int e = 0; e < 6; ++e) m = fmaxf(m, sc[e * 2 + h]);
    float ssum = 0.f;
    #pragma unroll
    for (int e = 0; e < 6; ++e) { float ex = expf(sc[e * 2 + h] - m); alpha[e * 2 + h] = ex; ssum += ex; }
    const float inv = 1.f / ssum;
    #pragma unroll
    for (int e = 0; e < 6; ++e) alpha[e * 2 + h] *= inv;
  }
  __syncthreads();
  for (int c = tid; c < OD; c += 256) {
    const int h = c >> 8;
    float acc = 0.f;
    #pragma unroll
    for (int e = 0; e < 6; ++e) acc += alpha[e * 2 + h] * rows[e][c];
    ctx[(size_t)i * OD + c] = acc + bias[c] + cmean[c];
  }
}

// ---------- fused epilogue: LN1 -> LN2 -> GELU -> 18-way classifier ----------
__global__ __launch_bounds__(256) void epilogue_kernel(const float* __restrict__ inst,
    const float* __restrict__ attn, const float* __restrict__ g1, const float* __restrict__ b1,
    const float* __restrict__ g2, const float* __restrict__ b2, const float* __restrict__ gw,
    const float* __restrict__ gb, const float* __restrict__ temp, float* __restrict__ out) {
  __shared__ float buf[HIDD];
  __shared__ float red[4];
  const int i = blockIdx.x;
  const int tid = threadIdx.x;
  const int lane = tid & 63, w = tid >> 6;
  size_t base = (size_t)i * HIDD;
  float v0 = inst[base + tid]       + attn[base + tid];
  float v1 = inst[base + tid + 256] + attn[base + tid + 256];
  float v2 = inst[base + tid + 512] + attn[base + tid + 512];

  float s = v0 + v1 + v2;
  #pragma unroll
  for (int off = 32; off; off >>= 1) s += __shfl_down(s, off);
  if (lane == 0) red[w] = s;
  __syncthreads();
  float mean = (red[0] + red[1] + red[2] + red[3]) * (1.f / HIDD);
  __syncthreads();
  float e0 = v0 - mean, e1 = v1 - mean, e2 = v2 - mean;
  s = e0 * e0 + e1 * e1 + e2 * e2;
  #pragma unroll
  for (int off = 32; off; off >>= 1) s += __shfl_down(s, off);
  if (lane == 0) red[w] = s;
  __syncthreads();
  float rstd = rsqrtf((red[0] + red[1] + red[2] + red[3]) * (1.f / HIDD) + LN_EPS);
  __syncthreads();
  float y0 = e0 * rstd * g1[tid]       + b1[tid];
  float y1 = e1 * rstd * g1[tid + 256] + b1[tid + 256];
  float y2 = e2 * rstd * g1[tid + 512] + b1[tid + 512];

  s = y0 + y1 + y2;
  #pragma unroll
  for (int off = 32; off; off >>= 1) s += __shfl_down(s, off);
  if (lane == 0) red[w] = s;
  __syncthreads();
  float mean2 = (red[0] + red[1] + red[2] + red[3]) * (1.f / HIDD);
  __syncthreads();
  float f0 = y0 - mean2, f1 = y1 - mean2, f2 = y2 - mean2;
  s = f0 * f0 + f1 * f1 + f2 * f2;
  #pragma unroll
  for (int off = 32; off; off >>= 1) s += __shfl_down(s, off);
  if (lane == 0) red[w] = s;
  __syncthreads();
  float rstd2 = rsqrtf((red[0] + red[1] + red[2] + red[3]) * (1.f / HIDD) + LN_EPS);
  float z0 = f0 * rstd2 * g2[tid]       + b2[tid];
  float z1 = f1 * rstd2 * g2[tid + 256] + b2[tid + 256];
  float z2 = f2 * rstd2 * g2[tid + 512] + b2[tid + 512];
  buf[tid]       = 0.5f * z0 * (1.f + erff(z0 * 0.70710678118654752f));
  buf[tid + 256] = 0.5f * z1 * (1.f + erff(z1 * 0.70710678118654752f));
  buf[tid + 512] = 0.5f * z2 * (1.f + erff(z2 * 0.70710678118654752f));
  __syncthreads();

  float invT = 1.f / temp[0];
  for (int c = w; c < NCLS; c += 4) {
    const float* wr = gw + (size_t)c * HIDD;
    float acc = 0.f;
    for (int d = lane; d < HIDD; d += 64) acc += buf[d] * wr[d];
    #pragma unroll
    for (int off = 32; off; off >>= 1) acc += __shfl_down(acc, off);
    if (lane == 0) out[(size_t)i * NCLS + c] = (acc + gb[c]) * invT;
  }
}

// ---------------------------------------------------------------------------
extern "C" void kernel_launch(void* const* d_in, const int* in_sizes, int n_in,
                              void* d_out, int out_size, void* d_ws, size_t ws_size,
                              hipStream_t stream) {
  (void)in_sizes; (void)n_in; (void)out_size; (void)ws_size;
  const float* X       = (const float*)d_in[0];
  const int*   cei     = (const int*)  d_in[1];
  const float* cemb    = (const float*)d_in[2];
  const float* gc_wl   = (const float*)d_in[3];
  const float* gc_bl   = (const float*)d_in[4];
  const float* gc_wr   = (const float*)d_in[5];
  const float* gc_br   = (const float*)d_in[6];
  const float* gc_att  = (const float*)d_in[7];
  const float* gc_bias = (const float*)d_in[8];
  const float* gi_wl   = (const float*)d_in[9];
  const float* gi_bl   = (const float*)d_in[10];
  const float* gi_wr   = (const float*)d_in[11];
  const float* gi_br   = (const float*)d_in[12];
  const float* gi_att  = (const float*)d_in[13];
  const float* gi_bias = (const float*)d_in[14];
  // d_in[15]=q_w, d_in[16]=q_b: cancel out of the forward value (seq_len 1)
  const float* ctx_w   = (const float*)d_in[17];
  const float* ctx_b   = (const float*)d_in[18];
  const float* wv      = (const float*)d_in[19];
  const float* bv      = (const float*)d_in[20];
  const float* wo      = (const float*)d_in[21];
  const float* bo      = (const float*)d_in[22];
  const float* ln1_g   = (const float*)d_in[23];
  const float* ln1_b   = (const float*)d_in[24];
  const float* ln2_g   = (const float*)d_in[25];
  const float* ln2_b   = (const float*)d_in[26];
  const float* gw_w    = (const float*)d_in[27];
  const float* gw_b    = (const float*)d_in[28];
  const float* temp    = (const float*)d_in[29];
  float* out = (float*)d_out;

  // ---- workspace layout (f32 units). R1,R2,R3 are 4.19M f32 each. ----
  // Liveness (write-before-read on every call):
  //   R1: pck (dist->cand_merge) -> xlr head (gemm->inst_gat) -> ctxh
  //   R2: T1 (small_nn->small_nn) -> xlr tail -> attnb head (gemm->epilogue)
  //   R3: Xh+wlrh (casts->dist/gemms) -> ctx (inst_gat->tobf16) -> attnb tail
  //   R4: x2, W3, w3h, t1b, bp, bb, cand, knn, xlc, xrc, cmean (no overlays)
  float* ws  = (float*)d_ws;
  float* R1  = ws;
  float* R2  = R1 + (size_t)NN * OD;
  float* R3  = R2 + (size_t)NN * OD;
  float* R4  = R3 + (size_t)NN * OD;

  // R4 sublayout
  float* x2    = R4;                                   // 8192
  float* W3    = x2 + NN;                              // 768*512 f32
  ushort* w3h  = (ushort*)(W3 + (size_t)HIDD * OD);    // 768*512 bf16
  float* t1b   = (float*)(w3h + (size_t)HIDD * OD);    // 768
  float* bp    = t1b + HIDD;                           // 768
  float* bb    = bp + HIDD;                            // 1024 stacked bias
  int*   cand  = (int*)(bb + 2 * OD);                  // 8192*8
  int*   knn   = cand + NN * 8;                        // 8192*5
  float* xlc   = (float*)(knn + NN * 5);               // 18*512
  float* xrc   = xlc + NCLS * OD;                      // 18*512
  float* cmean = xrc + NCLS * OD;                      // 512

  // aliases
  unsigned* pck = (unsigned*)R1;                       // [16][8192][8] u32 = 4 MB
  float* xlr   = R1;                                   // 8192*1024 f32 (R1+R2)
  ushort* ctxh = (ushort*)R1;                          // 8192*512 bf16 (xlr dead)
  float* T1    = R2;                                   // 768*512 f32 (dead before xlr)
  float* ctx   = R3;
  ushort* Xh   = (ushort*)R3;                          // 8192*768 bf16 (dead before ctx)
  ushort* wlrh = (ushort*)(R3 + (size_t)NN * HIDD / 2);// 1024*768 bf16 stacked wl|wr
  float* attnb = R2;   // 8192*768 f32, spans R2 + head of R3 (both dead)

  // --- class path -> cmean[512] (independent) ---
  small_lin_kernel<<<(NCLS * OD + 255) / 256, 256, 0, stream>>>(cemb, gc_wl, gc_bl, xlc, NCLS, HIDD, OD);
  small_lin_kernel<<<(NCLS * OD + 255) / 256, 256, 0, stream>>>(cemb, gc_wr, gc_br, xrc, NCLS, HIDD, OD);
  class_gat_kernel<<<1, 256, 0, stream>>>(cei, xlc, xrc, gc_att, gc_bias, cmean);

  // --- fold attention weights: W3 = wo @ wv @ ctx_w, bp = wo@(wv@ctx_b+bv)+bo ---
  small_nn_kernel<<<(HIDD * OD + 255) / 256, 256, 0, stream>>>(wv, ctx_w, T1, HIDD, HIDD, OD);
  small_nn_kernel<<<(HIDD * OD + 255) / 256, 256, 0, stream>>>(wo, T1, W3, HIDD, HIDD, OD);
  small_lin_kernel<<<(HIDD + 255) / 256, 256, 0, stream>>>(ctx_b, wv, bv, t1b, 1, HIDD, HIDD);
  small_lin_kernel<<<(HIDD + 255) / 256, 256, 0, stream>>>(t1b, wo, bo, bp, 1, HIDD, HIDD);

  // --- bf16 casts + bias stack (T1 dead now) ---
  tobf16_kernel<<<(HIDD * OD / 4 + 255) / 256, 256, 0, stream>>>(W3, w3h, HIDD * OD / 4);
  tobf16_kernel<<<(OD * HIDD / 4 + 255) / 256, 256, 0, stream>>>(gi_wl, wlrh, OD * HIDD / 4);
  tobf16_kernel<<<(OD * HIDD / 4 + 255) / 256, 256, 0, stream>>>(gi_wr, wlrh + (size_t)OD * HIDD, OD * HIDD / 4);
  rowcast_kernel<<<NN / 4, 256, 0, stream>>>(X, Xh, x2);
  stack_bias_kernel<<<4, 256, 0, stream>>>(gi_bl, gi_br, bb);

  // --- kNN: approx bf16 MFMA top-8 (packed keys) -> merge -> exact refine ---
  dist_topk_mfma<<<dim3(NN / 128, NGRP), 256, 0, stream>>>(Xh, x2, pck);
  cand_merge_kernel<<<NN / 256, 256, 0, stream>>>(pck, cand);
  refine_kernel<<<NN / 4, 256, 0, stream>>>(X, x2, cand, knn);

  // --- instance GATv2: fused xl|xr projection (pck dead) ---
  gemm_nt_mfma<<<dim3(NN / 128, (2 * OD) / 128), 256, 0, stream>>>(Xh, wlrh, bb, xlr, 2 * OD, HIDD);
  inst_gat_kernel<<<NN, 256, 0, stream>>>(xlr, knn, gi_att, gi_bias, cmean, ctx);

  // --- attention chain: attn = ctx @ W3^T + bp (ctx -> bf16 first) ---
  tobf16_kernel<<<(NN * OD / 4 + 255) / 256, 256, 0, stream>>>(ctx, ctxh, NN * OD / 4);
  gemm_nt_mfma<<<dim3(NN / 128, HIDD / 128), 256, 0, stream>>>(ctxh, w3h, bp, attnb, HIDD, OD);

  // --- LN -> LN -> GELU -> classifier ---
  epilogue_kernel<<<NN, 256, 0, stream>>>(X, attnb, ln1_g, ln1_b, ln2_g, ln2_b, gw_w, gw_b, temp, out);
}

// Round 7
// 941.176 us; speedup vs baseline: 4.1852x; 1.5789x over previous
//
#include <hip/hip_runtime.h>
#include <hip/hip_bf16.h>
#include <hip/hip_fp16.h>
#include <math.h>

#define NN 8192
#define HIDD 768
#define NCLS 18
#define OD 512          // HEADS*GD = 2*256
#define ETOT 342        // 324 class edges + 18 self loops
#define NGRP 16         // column groups for dist kernel
#define NEG 0.2f
#define LN_EPS 1e-5f

typedef __attribute__((ext_vector_type(8))) short bf16x8;
typedef __attribute__((ext_vector_type(4))) float f32x4;

// ---------- sorted top-5 insert (static indices, stays in registers) --------
__device__ __forceinline__ void top5_insert(float s, int idx,
    float& d0, float& d1, float& d2, float& d3, float& d4,
    int& i0, int& i1, int& i2, int& i3, int& i4) {
  if (s >= d4) return;
  if (s < d3) {
    d4 = d3; i4 = i3;
    if (s < d2) {
      d3 = d2; i3 = i2;
      if (s < d1) {
        d2 = d1; i2 = i1;
        if (s < d0) { d1 = d0; i1 = i0; d0 = s; i0 = idx; }
        else        { d1 = s;  i1 = idx; }
      } else { d2 = s; i2 = idx; }
    } else { d3 = s; i3 = idx; }
  } else { d4 = s; i4 = idx; }
}

// ---------- top-8 insert on packed u32 keys (rank-based, static indices) ----
__device__ __forceinline__ void top8k_insert(unsigned key, unsigned (&kk)[8]) {
  if (key >= kk[7]) return;
  int rank = 0;
  #pragma unroll
  for (int k = 0; k < 7; ++k) rank += (key >= kk[k]) ? 1 : 0;
  #pragma unroll
  for (int k = 7; k >= 1; --k) if (k > rank) kk[k] = kk[k-1];
  #pragma unroll
  for (int k = 0; k < 8; ++k) if (k == rank) kk[k] = key;
}

// ---------- async global->LDS 16B (used only in gemm_nt_mfma) ---------------
__device__ __forceinline__ void stage16(const void* g, void* l) {
  __builtin_amdgcn_global_load_lds(
      (const __attribute__((address_space(1))) unsigned int*)g,
      (__attribute__((address_space(3))) unsigned int*)l, 16, 0, 0);
}

__device__ __forceinline__ ushort f2b(float v) {
  __hip_bfloat16 b = __float2bfloat16(v);
  return *(ushort*)&b;
}

// ============ prep1 mega-kernel: all independent preamble tasks ==============
// blocks [0,2048): rowcast X->Xh + x2
//        [2048,2816): cast gi_wl / gi_wr -> wlrh (bf16)
//        [2816,2888): xlc / xrc class projections
//        [2888,4424): T1 = wv @ ctx_w (fp32)
//        [4424,4427): t1b = wv @ ctx_b + bv
//        [4427,4431): bb = stack(gi_bl, gi_br)
__global__ __launch_bounds__(256) void prep1_kernel(
    const float* __restrict__ X, ushort* __restrict__ Xh, float* __restrict__ x2,
    const float* __restrict__ gi_wl, const float* __restrict__ gi_wr,
    ushort* __restrict__ wlrh,
    const float* __restrict__ cemb, const float* __restrict__ gc_wl,
    const float* __restrict__ gc_bl, const float* __restrict__ gc_wr,
    const float* __restrict__ gc_br, float* __restrict__ xlc, float* __restrict__ xrc,
    const float* __restrict__ wv, const float* __restrict__ ctx_w, float* __restrict__ T1,
    const float* __restrict__ ctx_b, const float* __restrict__ bv, float* __restrict__ t1b,
    const float* __restrict__ gi_bl, const float* __restrict__ gi_br,
    float* __restrict__ bb) {
  const int bx = blockIdx.x, tid = threadIdx.x;
  if (bx < 2048) {                       // ---- rowcast + rownorm ----
    const int row = bx * 4 + (tid >> 6);
    const int lane = tid & 63;
    const float4* src = (const float4*)(X + (size_t)row * HIDD);
    ushort4* dst = (ushort4*)(Xh + (size_t)row * HIDD);
    float s = 0.f;
    #pragma unroll
    for (int q = 0; q < 3; ++q) {
      float4 v = src[lane + q * 64];
      s += v.x * v.x + v.y * v.y + v.z * v.z + v.w * v.w;
      dst[lane + q * 64] = make_ushort4(f2b(v.x), f2b(v.y), f2b(v.z), f2b(v.w));
    }
    #pragma unroll
    for (int off = 32; off; off >>= 1) s += __shfl_down(s, off);
    if (lane == 0) x2[row] = s;
  } else if (bx < 2816) {                // ---- weight casts ----
    int rel = bx - 2048;
    const float* src = gi_wl; ushort* dst = wlrh;
    if (rel >= 384) { rel -= 384; src = gi_wr; dst = wlrh + (size_t)OD * HIDD; }
    const int i = rel * 256 + tid;       // < 98304 = OD*HIDD/4
    float4 v = ((const float4*)src)[i];
    ((ushort4*)dst)[i] = make_ushort4(f2b(v.x), f2b(v.y), f2b(v.z), f2b(v.w));
  } else if (bx < 2888) {                // ---- class xlc/xrc ----
    int t = (bx - 2816) * 256 + tid;
    const float* W; const float* b; float* Y;
    if (t < NCLS * OD) { W = gc_wl; b = gc_bl; Y = xlc; }
    else { t -= NCLS * OD; W = gc_wr; b = gc_br; Y = xrc; }
    const int row = t / OD, o = t - row * OD;
    const float* xr = cemb + (size_t)row * HIDD;
    const float* wr = W + (size_t)o * HIDD;
    float acc = 0.f;
    for (int k = 0; k < HIDD; ++k) acc += xr[k] * wr[k];
    Y[t] = acc + b[o];
  } else if (bx < 4424) {                // ---- T1 = wv @ ctx_w ----
    const int idx = (bx - 2888) * 256 + tid;
    const int i = idx >> 9, j = idx & 511;
    float acc = 0.f;
    for (int k = 0; k < HIDD; ++k) acc += wv[(size_t)i * HIDD + k] * ctx_w[(size_t)k * OD + j];
    T1[idx] = acc;
  } else if (bx < 4427) {                // ---- t1b ----
    const int t = (bx - 4424) * 256 + tid;
    if (t < HIDD) {
      float acc = 0.f;
      for (int k = 0; k < HIDD; ++k) acc += ctx_b[k] * wv[(size_t)t * HIDD + k];
      t1b[t] = acc + bv[t];
    }
  } else {                               // ---- bias stack ----
    const int t = (bx - 4427) * 256 + tid;
    if (t < OD) bb[t] = gi_bl[t];
    else if (t < 2 * OD) bb[t] = gi_br[t - OD];
  }
}

// ============ prep2: W3 fold (bf16 out) + bp + class-graph GAT ===============
// blocks [0,1536): w3h = bf16(wo @ T1)
//        [1536,1539): bp = wo @ t1b + bo
//        1539: class GATv2 -> cmean
__global__ __launch_bounds__(256) void prep2_kernel(
    const float* __restrict__ wo, const float* __restrict__ T1,
    ushort* __restrict__ w3h, const float* __restrict__ t1b,
    const float* __restrict__ bo, float* __restrict__ bp,
    const int* __restrict__ cei, const float* __restrict__ xlc,
    const float* __restrict__ xrc, const float* __restrict__ gc_att,
    const float* __restrict__ gc_bias, float* __restrict__ cmean) {
  __shared__ float sc[ETOT * 2];
  __shared__ int es[ETOT], ed[ETOT];
  __shared__ float mx[NCLS][2], sm[NCLS][2];
  const int bx = blockIdx.x, tid = threadIdx.x;
  if (bx < 1536) {                       // ---- w3h ----
    const int idx = bx * 256 + tid;
    const int i = idx >> 9, j = idx & 511;
    float acc = 0.f;
    for (int k = 0; k < HIDD; ++k) acc += wo[(size_t)i * HIDD + k] * T1[(size_t)k * OD + j];
    w3h[idx] = f2b(acc);
  } else if (bx < 1539) {                // ---- bp ----
    const int t = (bx - 1536) * 256 + tid;
    if (t < HIDD) {
      float acc = 0.f;
      for (int k = 0; k < HIDD; ++k) acc += t1b[k] * wo[(size_t)t * HIDD + k];
      bp[t] = acc + bo[t];
    }
  } else {                               // ---- class GAT (1 block) ----
    for (int e = tid; e < ETOT; e += 256) {
      if (e < 324) { es[e] = cei[e]; ed[e] = cei[324 + e]; }
      else         { es[e] = e - 324; ed[e] = e - 324; }
    }
    __syncthreads();
    const int lane = tid & 63, w = tid >> 6;
    for (int t = w; t < ETOT * 2; t += 4) {
      const int e = t >> 1, h = t & 1;
      const float* xlr = xlc + (size_t)es[e] * OD + h * 256;
      const float* xrr = xrc + (size_t)ed[e] * OD + h * 256;
      const float* ar  = gc_att + h * 256;
      float s = 0.f;
      for (int d = lane; d < 256; d += 64) {
        float v = xlr[d] + xrr[d];
        v = v > 0.f ? v : NEG * v;
        s += v * ar[d];
      }
      #pragma unroll
      for (int off = 32; off; off >>= 1) s += __shfl_down(s, off);
      if (lane == 0) sc[t] = s;
    }
    __syncthreads();
    if (tid < NCLS * 2) {
      const int d = tid >> 1, h = tid & 1;
      float m = -3e38f;
      for (int e = 0; e < ETOT; ++e) if (ed[e] == d) m = fmaxf(m, sc[e * 2 + h]);
      float ssum = 0.f;
      for (int e = 0; e < ETOT; ++e) if (ed[e] == d) ssum += expf(sc[e * 2 + h] - m);
      mx[d][h] = m; sm[d][h] = 1.f / ssum;
    }
    __syncthreads();
    for (int t = tid; t < ETOT * 2; t += 256) {
      const int e = t >> 1, h = t & 1;
      sc[t] = expf(sc[t] - mx[ed[e]][h]) * sm[ed[e]][h];
    }
    __syncthreads();
    for (int c = tid; c < OD; c += 256) {
      const int h = c >> 8;
      float acc = 0.f;
      for (int e = 0; e < ETOT; ++e) acc += sc[e * 2 + h] * xlc[(size_t)es[e] * OD + c];
      cmean[c] = acc * (1.f / 18.f) + gc_bias[c];
    }
  }
}

// ---------- stage 1: bf16 MFMA distances + per-row approx top-8 (packed keys)
// 128x128 tile / block, BK=64, NGRP column groups, 4 blocks/CU (33 KB LDS,
// <=128 VGPR). Register prefetch: kt+1's global loads issue under kt's MFMAs.
__global__ __launch_bounds__(256, 4) void dist_topk_mfma(
    const ushort* __restrict__ Xh, const float* __restrict__ x2,
    unsigned* __restrict__ pck) {
  __shared__ __align__(16) char lds[32768];   // sA|sB staging ∪ Dk keys ∪ merge
  __shared__ float c2s[128];
  char* const sA = lds;
  char* const sB = lds + 16384;
  ushort* const Dk = (ushort*)lds;            // 128x128 u16 keys = 32 KB
  unsigned* const ck = (unsigned*)lds;        // merge [256][8] u32 = 8 KB

  const int tid = threadIdx.x;
  const int lane = tid & 63, wid = tid >> 6;
  const int fr = lane & 15, fq = lane >> 4;
  const int r0 = blockIdx.x * 128;
  const int grp = blockIdx.y;
  const int wr = (wid >> 1) * 64, wc = (wid & 1) * 64;
  const int srow = tid & 127, shalf = tid >> 7;

  // per-q staging geometry (row, chunk) and u32 offsets (ushort units)
  unsigned aoff[4], boff0[4]; int wiq[4];
  #pragma unroll
  for (int q = 0; q < 4; ++q) {
    const int chunkid = q * 256 + tid;
    const int row = chunkid >> 3, cc = chunkid & 7;
    aoff[q]  = (unsigned)((r0 + row) * HIDD + cc * 8);
    boff0[q] = (unsigned)(row * HIDD + cc * 8);        // add c0*HIDD per tile
    wiq[q]   = row * 128 + ((cc ^ (row & 7)) << 4);
  }

  unsigned keys[8];
  #pragma unroll
  for (int k = 0; k < 8; ++k) keys[k] = 0xFFFFFFFFu;

  for (int jt = 0; jt < (NN / NGRP) / 128; ++jt) {
    const int c0 = grp * (NN / NGRP) + jt * 128;
    const unsigned cb = (unsigned)c0 * HIDD;
    __syncthreads();                         // prev tile scan done (LDS free)
    if (tid < 128) c2s[tid] = x2[c0 + tid];
    // prologue: load kt=0 into regs
    bf16x8 va[4], vb[4];
    #pragma unroll
    for (int q = 0; q < 4; ++q) {
      va[q] = *(const bf16x8*)(Xh + aoff[q]);
      vb[q] = *(const bf16x8*)(Xh + cb + boff0[q]);
    }
    f32x4 acc[4][4] = {};
    for (int kt = 0; kt < HIDD; kt += 64) {
      __syncthreads();                       // prior LDS readers done
      #pragma unroll
      for (int q = 0; q < 4; ++q) {
        *(bf16x8*)(sA + wiq[q]) = va[q];
        *(bf16x8*)(sB + wiq[q]) = vb[q];
      }
      __syncthreads();                       // staged data visible
      if (kt + 64 < HIDD) {                  // prefetch kt+1 under the MFMAs
        #pragma unroll
        for (int q = 0; q < 4; ++q) {
          va[q] = *(const bf16x8*)(Xh + aoff[q] + kt + 64);
          vb[q] = *(const bf16x8*)(Xh + cb + boff0[q] + kt + 64);
        }
      }
      #pragma unroll
      for (int kk = 0; kk < 2; ++kk) {
        bf16x8 bh[4];
        #pragma unroll
        for (int n = 0; n < 4; ++n) {
          const int br = wc + n * 16 + fr;
          bh[n] = *(const bf16x8*)(sB + br * 128 + (((kk * 4 + fq) ^ (br & 7)) << 4));
        }
        #pragma unroll
        for (int m = 0; m < 4; ++m) {
          const int ar = wr + m * 16 + fr;
          const bf16x8 a = *(const bf16x8*)(sA + ar * 128 + (((kk * 4 + fq) ^ (ar & 7)) << 4));
          #pragma unroll
          for (int n = 0; n < 4; ++n)
            acc[m][n] = __builtin_amdgcn_mfma_f32_16x16x32_bf16(a, bh[n], acc[m][n], 0, 0, 0);
        }
      }
    }
    __syncthreads();                         // all frag reads done; overlay Dk
    #pragma unroll
    for (int n = 0; n < 4; ++n) {
      const int col = wc + n * 16 + fr;
      const float c2 = c2s[col] - 768.0f;
      #pragma unroll
      for (int m = 0; m < 4; ++m) {
        #pragma unroll
        for (int j = 0; j < 4; ++j) {
          const int row = wr + m * 16 + fq * 4 + j;
          const float s = c2 - 2.0f * acc[m][n][j];
          const ushort u = __half_as_ushort(__float2half(s));
          const ushort k16 = (u & 0x8000) ? (ushort)(~u) : (ushort)(u | 0x8000);
          Dk[row * 128 + ((col + row) & 127)] = k16;
        }
      }
    }
    __syncthreads();
    {
      const int r = srow;
      for (int c = 0; c < 64; ++c) {
        const int col = shalf * 64 + c;
        const unsigned key =
            ((unsigned)Dk[r * 128 + ((col + r) & 127)] << 16) | (unsigned)(c0 + col);
        top8k_insert(key, keys);
      }
    }
  }
  __syncthreads();
  #pragma unroll
  for (int k = 0; k < 8; ++k) ck[tid * 8 + k] = keys[k];
  __syncthreads();
  if (tid < 128) {
    unsigned mk[8];
    #pragma unroll
    for (int k = 0; k < 8; ++k) mk[k] = ck[tid * 8 + k];
    const int src = tid + 128;
    #pragma unroll
    for (int k = 0; k < 8; ++k) top8k_insert(ck[src * 8 + k], mk);
    const size_t base = ((size_t)grp * NN + (r0 + tid)) * 8;   // [g][row][8]
    #pragma unroll
    for (int k = 0; k < 8; ++k) pck[base + k] = mk[k];
  }
}

// ---------- merge NGRP key lists -> per-row top-8 candidate indices ----------
__global__ __launch_bounds__(256) void cand_merge_kernel(const unsigned* __restrict__ pck,
    int* __restrict__ cand) {
  const int row = blockIdx.x * 256 + threadIdx.x;
  if (row >= NN) return;
  unsigned best[8];
  #pragma unroll
  for (int k = 0; k < 8; ++k) best[k] = 0xFFFFFFFFu;
  for (int g = 0; g < NGRP; ++g) {
    const size_t base = ((size_t)g * NN + row) * 8;
    #pragma unroll
    for (int k = 0; k < 8; ++k) top8k_insert(pck[base + k], best);
  }
  #pragma unroll
  for (int k = 0; k < 8; ++k) cand[row * 8 + k] = (int)(best[k] & 0xFFFFu);
}

// ---------- stage 2: exact fp32 refine of 8 candidates -> exact top-5 --------
__global__ __launch_bounds__(256) void refine_kernel(const float* __restrict__ X,
    const float* __restrict__ x2, const int* __restrict__ cand, int* __restrict__ knn) {
  const int row = blockIdx.x * 4 + (threadIdx.x >> 6);
  const int lane = threadIdx.x & 63;
  int c[8];
  #pragma unroll
  for (int k = 0; k < 8; ++k) c[k] = cand[row * 8 + k];
  const float4* xi = (const float4*)(X + (size_t)row * HIDD);
  float acc[8] = {};
  #pragma unroll
  for (int q = 0; q < 3; ++q) {
    const float4 a = xi[lane + q * 64];
    #pragma unroll
    for (int k = 0; k < 8; ++k) {
      const float4 b = ((const float4*)(X + (size_t)c[k] * HIDD))[lane + q * 64];
      acc[k] += a.x * b.x + a.y * b.y + a.z * b.z + a.w * b.w;
    }
  }
  #pragma unroll
  for (int k = 0; k < 8; ++k) {
    #pragma unroll
    for (int off = 32; off; off >>= 1) acc[k] += __shfl_down(acc[k], off);
  }
  if (lane == 0) {
    float d0 = 3e38f, d1 = 3e38f, d2 = 3e38f, d3 = 3e38f, d4 = 3e38f;
    int i0 = 0, i1 = 0, i2 = 0, i3 = 0, i4 = 0;
    #pragma unroll
    for (int k = 0; k < 8; ++k) {
      const float s = x2[c[k]] - 2.0f * acc[k];
      top5_insert(s, c[k], d0, d1, d2, d3, d4, i0, i1, i2, i3, i4);
    }
    knn[row * 5 + 0] = i0; knn[row * 5 + 1] = i1; knn[row * 5 + 2] = i2;
    knn[row * 5 + 3] = i3; knn[row * 5 + 4] = i4;
  }
}

// ---------- bf16 MFMA GEMM: C[8192,Nc] = A @ B^T + bias ----------------------
__global__ __launch_bounds__(256) void gemm_nt_mfma(const ushort* __restrict__ A,
    const ushort* __restrict__ B, const float* __restrict__ bias,
    float* __restrict__ C, int Nc, int K) {
  __shared__ char lds[32768];
  char* const pA = lds;
  char* const pB = lds + 16384;
  const int tid = threadIdx.x;
  const int lane = tid & 63, wid = tid >> 6;
  const int fr = lane & 15, fq = lane >> 4;
  const int r0 = blockIdx.x * 128;
  const int c0 = blockIdx.y * 128;
  const int wr = (wid >> 1) * 64, wc = (wid & 1) * 64;
  f32x4 acc[4][4] = {};
  for (int kt = 0; kt < K; kt += 64) {
    __syncthreads();
    #pragma unroll
    for (int q = 0; q < 4; ++q) {
      const int chunk = wid * 256 + q * 64 + lane;
      const int row = chunk >> 3;
      const int lc = (chunk & 7) ^ (row & 7);
      const int ld = wid * 4096 + q * 1024;
      stage16((const char*)A + ((size_t)(r0 + row) * K + kt) * 2 + (size_t)lc * 16, pA + ld);
      stage16((const char*)B + ((size_t)(c0 + row) * K + kt) * 2 + (size_t)lc * 16, pB + ld);
    }
    __syncthreads();
    #pragma unroll
    for (int kk = 0; kk < 2; ++kk) {
      bf16x8 ah[4], bh[4];
      #pragma unroll
      for (int m = 0; m < 4; ++m) {
        const int ar = wr + m * 16 + fr;
        ah[m] = *(const bf16x8*)(pA + ar * 128 + (((kk * 4 + fq) ^ (ar & 7)) << 4));
      }
      #pragma unroll
      for (int n = 0; n < 4; ++n) {
        const int br = wc + n * 16 + fr;
        bh[n] = *(const bf16x8*)(pB + br * 128 + (((kk * 4 + fq) ^ (br & 7)) << 4));
      }
      #pragma unroll
      for (int m = 0; m < 4; ++m)
        #pragma unroll
        for (int n = 0; n < 4; ++n)
          acc[m][n] = __builtin_amdgcn_mfma_f32_16x16x32_bf16(ah[m], bh[n], acc[m][n], 0, 0, 0);
    }
  }
  #pragma unroll
  for (int n = 0; n < 4; ++n) {
    const int cc = c0 + wc + n * 16 + fr;
    const float bs = bias[cc];
    #pragma unroll
    for (int m = 0; m < 4; ++m) {
      #pragma unroll
      for (int j = 0; j < 4; ++j) {
        const int rr = r0 + wr + m * 16 + fq * 4 + j;
        C[(size_t)rr * Nc + cc] = acc[m][n][j] + bs;
      }
    }
  }
}

// ---------- instance GATv2; xlr packed [N][1024]; ctx written bf16 -----------
__global__ __launch_bounds__(256) void inst_gat_kernel(const float* __restrict__ xlr,
    const int* __restrict__ knn, const float* __restrict__ att,
    const float* __restrict__ bias, const float* __restrict__ cmean,
    ushort* __restrict__ ctxh) {
  __shared__ float rows[7][512];   // 6 neighbor xl rows + own xr row
  __shared__ float sc[12];
  __shared__ float alpha[12];
  __shared__ int nbr[6];
  const int i = blockIdx.x;
  const int tid = threadIdx.x;
  if (tid < 5) nbr[tid] = knn[i * 5 + tid];
  else if (tid == 5) nbr[5] = i;   // explicit self loop
  __syncthreads();
  for (int t = tid; t < 7 * 128; t += 256) {
    const int rr = t >> 7, e4 = t & 127;
    const float* src = (rr < 6) ? (xlr + (size_t)nbr[rr] * 1024)
                                : (xlr + (size_t)i * 1024 + 512);
    ((float4*)rows[rr])[e4] = ((const float4*)src)[e4];
  }
  __syncthreads();
  const int lane = tid & 63, w = tid >> 6;
  for (int t = w; t < 12; t += 4) {
    const int e = t >> 1, h = t & 1;
    const float* ar = att + h * 256;
    float s = 0.f;
    #pragma unroll
    for (int q = 0; q < 4; ++q) {
      const int d = lane + q * 64;
      float v = rows[e][h * 256 + d] + rows[6][h * 256 + d];
      v = v > 0.f ? v : NEG * v;
      s += v * ar[d];
    }
    #pragma unroll
    for (int off = 32; off; off >>= 1) s += __shfl_down(s, off);
    if (lane == 0) sc[t] = s;
  }
  __syncthreads();
  if (tid < 2) {
    const int h = tid;
    float m = -3e38f;
    #pragma unroll
    for (int e = 0; e < 6; ++e) m = fmaxf(m, sc[e * 2 + h]);
    float ssum = 0.f;
    #pragma unroll
    for (int e = 0; e < 6; ++e) { float ex = expf(sc[e * 2 + h] - m); alpha[e * 2 + h] = ex; ssum += ex; }
    const float inv = 1.f / ssum;
    #pragma unroll
    for (int e = 0; e < 6; ++e) alpha[e * 2 + h] *= inv;
  }
  __syncthreads();
  for (int c = tid; c < OD; c += 256) {
    const int h = c >> 8;
    float acc = 0.f;
    #pragma unroll
    for (int e = 0; e < 6; ++e) acc += alpha[e * 2 + h] * rows[e][c];
    ctxh[(size_t)i * OD + c] = f2b(acc + bias[c] + cmean[c]);
  }
}

// ---------- fused epilogue: LN1 -> LN2 -> GELU -> 18-way classifier ----------
__global__ __launch_bounds__(256) void epilogue_kernel(const float* __restrict__ inst,
    const float* __restrict__ attn, const float* __restrict__ g1, const float* __restrict__ b1,
    const float* __restrict__ g2, const float* __restrict__ b2, const float* __restrict__ gw,
    const float* __restrict__ gb, const float* __restrict__ temp, float* __restrict__ out) {
  __shared__ float buf[HIDD];
  __shared__ float red[4];
  const int i = blockIdx.x;
  const int tid = threadIdx.x;
  const int lane = tid & 63, w = tid >> 6;
  size_t base = (size_t)i * HIDD;
  float v0 = inst[base + tid]       + attn[base + tid];
  float v1 = inst[base + tid + 256] + attn[base + tid + 256];
  float v2 = inst[base + tid + 512] + attn[base + tid + 512];

  float s = v0 + v1 + v2;
  #pragma unroll
  for (int off = 32; off; off >>= 1) s += __shfl_down(s, off);
  if (lane == 0) red[w] = s;
  __syncthreads();
  float mean = (red[0] + red[1] + red[2] + red[3]) * (1.f / HIDD);
  __syncthreads();
  float e0 = v0 - mean, e1 = v1 - mean, e2 = v2 - mean;
  s = e0 * e0 + e1 * e1 + e2 * e2;
  #pragma unroll
  for (int off = 32; off; off >>= 1) s += __shfl_down(s, off);
  if (lane == 0) red[w] = s;
  __syncthreads();
  float rstd = rsqrtf((red[0] + red[1] + red[2] + red[3]) * (1.f / HIDD) + LN_EPS);
  __syncthreads();
  float y0 = e0 * rstd * g1[tid]       + b1[tid];
  float y1 = e1 * rstd * g1[tid + 256] + b1[tid + 256];
  float y2 = e2 * rstd * g1[tid + 512] + b1[tid + 512];

  s = y0 + y1 + y2;
  #pragma unroll
  for (int off = 32; off; off >>= 1) s += __shfl_down(s, off);
  if (lane == 0) red[w] = s;
  __syncthreads();
  float mean2 = (red[0] + red[1] + red[2] + red[3]) * (1.f / HIDD);
  __syncthreads();
  float f0 = y0 - mean2, f1 = y1 - mean2, f2 = y2 - mean2;
  s = f0 * f0 + f1 * f1 + f2 * f2;
  #pragma unroll
  for (int off = 32; off; off >>= 1) s += __shfl_down(s, off);
  if (lane == 0) red[w] = s;
  __syncthreads();
  float rstd2 = rsqrtf((red[0] + red[1] + red[2] + red[3]) * (1.f / HIDD) + LN_EPS);
  float z0 = f0 * rstd2 * g2[tid]       + b2[tid];
  float z1 = f1 * rstd2 * g2[tid + 256] + b2[tid + 256];
  float z2 = f2 * rstd2 * g2[tid + 512] + b2[tid + 512];
  buf[tid]       = 0.5f * z0 * (1.f + erff(z0 * 0.70710678118654752f));
  buf[tid + 256] = 0.5f * z1 * (1.f + erff(z1 * 0.70710678118654752f));
  buf[tid + 512] = 0.5f * z2 * (1.f + erff(z2 * 0.70710678118654752f));
  __syncthreads();

  float invT = 1.f / temp[0];
  for (int c = w; c < NCLS; c += 4) {
    const float* wr = gw + (size_t)c * HIDD;
    float acc = 0.f;
    for (int d = lane; d < HIDD; d += 64) acc += buf[d] * wr[d];
    #pragma unroll
    for (int off = 32; off; off >>= 1) acc += __shfl_down(acc, off);
    if (lane == 0) out[(size_t)i * NCLS + c] = (acc + gb[c]) * invT;
  }
}

// ---------------------------------------------------------------------------
extern "C" void kernel_launch(void* const* d_in, const int* in_sizes, int n_in,
                              void* d_out, int out_size, void* d_ws, size_t ws_size,
                              hipStream_t stream) {
  (void)in_sizes; (void)n_in; (void)out_size; (void)ws_size;
  const float* X       = (const float*)d_in[0];
  const int*   cei     = (const int*)  d_in[1];
  const float* cemb    = (const float*)d_in[2];
  const float* gc_wl   = (const float*)d_in[3];
  const float* gc_bl   = (const float*)d_in[4];
  const float* gc_wr   = (const float*)d_in[5];
  const float* gc_br   = (const float*)d_in[6];
  const float* gc_att  = (const float*)d_in[7];
  const float* gc_bias = (const float*)d_in[8];
  const float* gi_wl   = (const float*)d_in[9];
  const float* gi_bl   = (const float*)d_in[10];
  const float* gi_wr   = (const float*)d_in[11];
  const float* gi_br   = (const float*)d_in[12];
  const float* gi_att  = (const float*)d_in[13];
  const float* gi_bias = (const float*)d_in[14];
  // d_in[15]=q_w, d_in[16]=q_b: cancel out of the forward value (seq_len 1)
  const float* ctx_w   = (const float*)d_in[17];
  const float* ctx_b   = (const float*)d_in[18];
  const float* wv      = (const float*)d_in[19];
  const float* bv      = (const float*)d_in[20];
  const float* wo      = (const float*)d_in[21];
  const float* bo      = (const float*)d_in[22];
  const float* ln1_g   = (const float*)d_in[23];
  const float* ln1_b   = (const float*)d_in[24];
  const float* ln2_g   = (const float*)d_in[25];
  const float* ln2_b   = (const float*)d_in[26];
  const float* gw_w    = (const float*)d_in[27];
  const float* gw_b    = (const float*)d_in[28];
  const float* temp    = (const float*)d_in[29];
  float* out = (float*)d_out;

  // ---- workspace layout (f32 units). R1,R2,R3 are 4.19M f32 each. ----
  // Order: prep1, prep2, dist, merge, refine, gemm_xlr, inst_gat, gemm_attn, epi
  // R1: pck (dist->merge) -> xlr head (gemm->inst_gat) -> attnb head
  // R2: T1 (prep1->prep2) -> xlr tail -> attnb mid
  // R3: Xh+wlrh (prep1 -> dist/gemm) -> ctxh (inst_gat->gemm_attn) | attnb tail
  //     [attnb = R1 base, 25MB spans R1+R2 only: 33.5MB >= 25MB, R3 untouched]
  // R4: x2, w3h, t1b, bp, bb, cand, knn, xlc, xrc, cmean (no overlays)
  float* ws  = (float*)d_ws;
  float* R1  = ws;
  float* R2  = R1 + (size_t)NN * OD;
  float* R3  = R2 + (size_t)NN * OD;
  float* R4  = R3 + (size_t)NN * OD;

  // R4 sublayout
  float* x2    = R4;                                   // 8192
  ushort* w3h  = (ushort*)(x2 + NN);                   // 768*512 bf16
  float* t1b   = (float*)(w3h + (size_t)HIDD * OD);    // 768
  float* bp    = t1b + HIDD;                           // 768
  float* bb    = bp + HIDD;                            // 1024 stacked bias
  int*   cand  = (int*)(bb + 2 * OD);                  // 8192*8
  int*   knn   = cand + NN * 8;                        // 8192*5
  float* xlc   = (float*)(knn + NN * 5);               // 18*512
  float* xrc   = xlc + NCLS * OD;                      // 18*512
  float* cmean = xrc + NCLS * OD;                      // 512

  // aliases
  unsigned* pck = (unsigned*)R1;                       // [16][8192][8] u32 = 4 MB
  float* xlr   = R1;                                   // 8192*1024 f32 (R1+R2)
  float* attnb = R1;                                   // 8192*768 f32 (R1+R2 head)
  float* T1    = R2;                                   // 768*512 f32 (dead before xlr)
  ushort* Xh   = (ushort*)R3;                          // 8192*768 bf16
  ushort* wlrh = (ushort*)(R3 + (size_t)NN * HIDD / 2);// 1024*768 bf16 stacked wl|wr
  ushort* ctxh = (ushort*)R3;                          // 8192*512 bf16 (Xh dead)

  // 1) all independent preamble tasks
  prep1_kernel<<<4431, 256, 0, stream>>>(X, Xh, x2, gi_wl, gi_wr, wlrh,
      cemb, gc_wl, gc_bl, gc_wr, gc_br, xlc, xrc,
      wv, ctx_w, T1, ctx_b, bv, t1b, gi_bl, gi_br, bb);
  // 2) W3 fold (bf16 out) + bp + class GAT
  prep2_kernel<<<1540, 256, 0, stream>>>(wo, T1, w3h, t1b, bo, bp,
      cei, xlc, xrc, gc_att, gc_bias, cmean);
  // 3) kNN approx pass (MFMA + packed-key top-8)
  dist_topk_mfma<<<dim3(NN / 128, NGRP), 256, 0, stream>>>(Xh, x2, pck);
  // 4) merge candidate lists (pck dead after)
  cand_merge_kernel<<<NN / 256, 256, 0, stream>>>(pck, cand);
  // 5) exact fp32 refine -> knn
  refine_kernel<<<NN / 4, 256, 0, stream>>>(X, x2, cand, knn);
  // 6) fused xl|xr projection (overwrites pck region)
  gemm_nt_mfma<<<dim3(NN / 128, (2 * OD) / 128), 256, 0, stream>>>(Xh, wlrh, bb, xlr, 2 * OD, HIDD);
  // 7) GAT aggregate -> ctxh bf16 (overwrites Xh region; Xh dead)
  inst_gat_kernel<<<NN, 256, 0, stream>>>(xlr, knn, gi_att, gi_bias, cmean, ctxh);
  // 8) attn = ctxh @ w3h^T + bp (xlr dead; attnb overlays R1+R2)
  gemm_nt_mfma<<<dim3(NN / 128, HIDD / 128), 256, 0, stream>>>(ctxh, w3h, bp, attnb, HIDD, OD);
  // 9) LN -> LN -> GELU -> classifier
  epilogue_kernel<<<NN, 256, 0, stream>>>(X, attnb, ln1_g, ln1_b, ln2_g, ln2_b, gw_w, gw_b, temp, out);
}